// Round 15
// baseline (246.213 us; speedup 1.0000x reference)
//
#include <hip/hip_runtime.h>
#include <math.h>

#define BB 16
#define CC 128
#define HH 128
#define WW 128
#define LL 4096

typedef short short8 __attribute__((ext_vector_type(8)));
typedef float f32x4 __attribute__((ext_vector_type(4)));

__device__ __forceinline__ ushort f2bf(float f) {
    union { float f; unsigned u; } un; un.f = f;
    unsigned u = un.u;
    u += 0x7fffu + ((u >> 16) & 1u);   // RNE
    return (ushort)(u >> 16);
}
__device__ __forceinline__ float bf2f(ushort h) {
    union { unsigned u; float f; } un; un.u = ((unsigned)h) << 16;
    return un.f;
}
__device__ __forceinline__ float fast_gelu(float xv) {
    float x2 = xv*xv;
    float arg = xv*(-2.3022100f - 0.1029436f*x2);
    float e = exp2f(arg);
    return xv*__builtin_amdgcn_rcpf(1.f + e);
}
__device__ __forceinline__ int swzkey(int r) { return (r & 3) ^ ((r >> 2) & 3); }

// ---- prep: cvec = proj@bv + proj_b ----
__global__ __launch_bounds__(128) void prep_cvec(
    const float* __restrict__ qkv_b, const float* __restrict__ proj_w,
    const float* __restrict__ proj_b, float* __restrict__ cvec)
{
    int t = threadIdx.x;
    float s = proj_b[t];
    const float* pr = proj_w + t*CC;
    const float* bv = qkv_b + 2*CC;
    for (int c = 0; c < CC; ++c) s += pr[c]*bv[c];
    cvec[t] = s;
}

// ---- guide = dwconv7x7_s2(gelu(bn(x))), bf16 out [b][c][64*64]  (R12 form) ----
__global__ __launch_bounds__(256) void guide_kernel(
    const float* __restrict__ x, const float* __restrict__ gamma,
    const float* __restrict__ beta, const float* __restrict__ mean,
    const float* __restrict__ var, const float* __restrict__ dww,
    const float* __restrict__ dwb, ushort* __restrict__ gw)
{
    int bc = blockIdx.x;
    int b = bc >> 7, c = bc & 127;
    int ty = blockIdx.y;
    __shared__ __align__(16) float g[69*144];
    int t = threadIdx.x;
    float wreg[49];
    #pragma unroll
    for (int k = 0; k < 49; ++k) wreg[k] = dww[c*49 + k];
    float bias = dwb[c];
    float scl = gamma[c] * rsqrtf(var[c] + 1e-5f);
    float sft = beta[c] - mean[c]*scl;
    const float* xb = x + (size_t)(b*CC + c)*HH*WW;
    int ihbase = 64*ty - 3;
    #pragma unroll
    for (int k = 0; k < 9; ++k) {
        int idx = k*256 + t;
        if (idx < 69*32) {
            int row = idx >> 5, ch = idx & 31;
            int ih = ihbase + row;
            float4 v4 = {0.f, 0.f, 0.f, 0.f};
            if ((unsigned)ih < 128u) {
                float4 xv = *(const float4*)(xb + ih*WW + 4*ch);
                v4.x = fast_gelu(xv.x*scl + sft);
                v4.y = fast_gelu(xv.y*scl + sft);
                v4.z = fast_gelu(xv.z*scl + sft);
                v4.w = fast_gelu(xv.w*scl + sft);
            }
            int f = (row >> 2) & 3;
            *(float4*)(g + row*144 + 4*((ch + 1) ^ f)) = v4;
        }
    }
    if (t < 138) {
        int row = t >> 1;
        int lc = (t & 1) ? 33 : 0;
        int f = (row >> 2) & 3;
        float4 z4 = {0.f, 0.f, 0.f, 0.f};
        *(float4*)(g + row*144 + 4*(lc ^ f)) = z4;
    }
    __syncthreads();
    int vg = t >> 4, owg = t & 15;
    float acc[2][4];
    #pragma unroll
    for (int v = 0; v < 2; ++v)
        #pragma unroll
        for (int hh = 0; hh < 4; ++hh) acc[v][hh] = bias;
    #pragma unroll
    for (int j = 0; j < 9; ++j) {
        int rr = 4*vg + j;
        int f = (rr >> 2) & 3;
        const float* grow = g + rr*144;
        float win[16];
        #pragma unroll
        for (int i = 0; i < 4; ++i) {
            float4 w4 = *(const float4*)(grow + 4*(((2*owg + i) ^ f)));
            win[4*i+0] = w4.x; win[4*i+1] = w4.y;
            win[4*i+2] = w4.z; win[4*i+3] = w4.w;
        }
        #pragma unroll
        for (int v = 0; v < 2; ++v) {
            int kh = j - 2*v;
            if (kh >= 0 && kh <= 6) {
                #pragma unroll
                for (int hh = 0; hh < 4; ++hh)
                    #pragma unroll
                    for (int kw = 0; kw < 7; ++kw)
                        acc[v][hh] += wreg[kh*7 + kw] * win[2*hh + kw + 1];
            }
        }
    }
    int orbase = 32*ty + 2*vg;
    ushort* gdst = gw + ((size_t)(b*CC + c) << 12);
    #pragma unroll
    for (int v = 0; v < 2; ++v) {
        uint2 pk;
        pk.x = (unsigned)f2bf(acc[v][0]) | ((unsigned)f2bf(acc[v][1]) << 16);
        pk.y = (unsigned)f2bf(acc[v][2]) | ((unsigned)f2bf(acc[v][3]) << 16);
        *(uint2*)(gdst + (orbase + v)*64 + 4*owg) = pk;
    }
}

// ---- Gram_m[i,j] = sum_l t0[i,l]*t_m[j,l]; kq=16; bf16-packed output + T partials ----
__global__ __launch_bounds__(512) void gram_kernel(
    const float* __restrict__ x, const ushort* __restrict__ gw,
    ushort* __restrict__ Gpart, float* __restrict__ Tg, float* __restrict__ Txg)
{
    __shared__ __align__(16) ushort tokb[2*3*128*32];
    int t = threadIdx.x;
    int blk = blockIdx.x;
    int b = blk >> 5, kq = (blk >> 1) & 15, grp = blk & 1;
    int lane = t & 63, wid = t >> 6;
    int l15 = lane & 15, kg = lane >> 4;
    int js = t >> 2, sub = t & 3;
    int keyj = swzkey(js);
    const float* xrow0 = x + ((size_t)(b*CC + js)*HH + grp)*WW;
    const ushort* gwrow = gw + ((size_t)(b*CC + js) << 12);
    f32x4 acc[8][3];
    #pragma unroll
    for (int i = 0; i < 8; ++i)
        #pragma unroll
        for (int q = 0; q < 3; ++q) acc[i][q] = (f32x4){0.f,0.f,0.f,0.f};
    float tacc = 0.f, ps0 = 0.f, ps1 = 0.f;
    int H0 = kq*4;
    float4 xa, xbv, xc, xd;
    uint4 gr;
    {
        const float* xp = xrow0 + (2*H0)*WW + sub*16;
        xa = *(const float4*)(xp);
        xbv = *(const float4*)(xp + 4);
        xc = *(const float4*)(xp + 8);
        xd = *(const float4*)(xp + 12);
        gr = *(const uint4*)(gwrow + H0*64 + sub*8);
    }
    for (int s = 0; s < 8; ++s) {
        int cur = s & 1;
        ushort* tb = tokb + cur*(3*128*32);
        if (grp == 0) {
            tacc += bf2f((ushort)gr.x) + bf2f((ushort)(gr.x >> 16))
                  + bf2f((ushort)gr.y) + bf2f((ushort)(gr.y >> 16))
                  + bf2f((ushort)gr.z) + bf2f((ushort)(gr.z >> 16))
                  + bf2f((ushort)gr.w) + bf2f((ushort)(gr.w >> 16));
        }
        ps0 += xa.x + xa.z + xbv.x + xbv.z + xc.x + xc.z + xd.x + xd.z;
        ps1 += xa.y + xa.w + xbv.y + xbv.w + xc.y + xc.w + xd.y + xd.w;
        {
            unsigned lo0 = (unsigned)f2bf(xa.x) | ((unsigned)f2bf(xa.z) << 16);
            unsigned lo1 = (unsigned)f2bf(xbv.x) | ((unsigned)f2bf(xbv.z) << 16);
            unsigned lo2 = (unsigned)f2bf(xc.x) | ((unsigned)f2bf(xc.z) << 16);
            unsigned lo3 = (unsigned)f2bf(xd.x) | ((unsigned)f2bf(xd.z) << 16);
            unsigned hi0 = (unsigned)f2bf(xa.y) | ((unsigned)f2bf(xa.w) << 16);
            unsigned hi1 = (unsigned)f2bf(xbv.y) | ((unsigned)f2bf(xbv.w) << 16);
            unsigned hi2 = (unsigned)f2bf(xc.y) | ((unsigned)f2bf(xc.w) << 16);
            unsigned hi3 = (unsigned)f2bf(xd.y) | ((unsigned)f2bf(xd.w) << 16);
            uint4 lov = {lo0, lo1, lo2, lo3};
            uint4 hiv = {hi0, hi1, hi2, hi3};
            int chs = (sub ^ keyj) << 3;
            *(uint4*)(tb + (1*128 + js)*32 + chs) = lov;
            *(uint4*)(tb + (2*128 + js)*32 + chs) = hiv;
            *(uint4*)(tb + (0*128 + js)*32 + chs) = gr;
        }
        if (s < 7) {
            int sn = s + 1;
            int h = H0 + (sn >> 1), whalf = sn & 1;
            const float* xp = xrow0 + (2*h)*WW + whalf*64 + sub*16;
            xa = *(const float4*)(xp);
            xbv = *(const float4*)(xp + 4);
            xc = *(const float4*)(xp + 8);
            xd = *(const float4*)(xp + 12);
            gr = *(const uint4*)(gwrow + h*64 + whalf*32 + sub*8);
        }
        __syncthreads();
        const ushort* tb2 = tokb + cur*(3*128*32);
        short8 af[8];
        #pragma unroll
        for (int f = 0; f < 8; ++f) {
            int row = f*16 + l15;
            af[f] = *(const short8*)(tb2 + row*32 + ((kg ^ swzkey(row)) << 3));
        }
        if (grp == 0) {
            #pragma unroll
            for (int q = 0; q < 3; ++q) {
                int nf = wid*3 + q;
                int pl = nf >> 3, jr = (nf & 7)*16 + l15;
                short8 bf = *(const short8*)(tb2 + (pl*128 + jr)*32 + ((kg ^ swzkey(jr)) << 3));
                #pragma unroll
                for (int f = 0; f < 8; ++f)
                    acc[f][q] = __builtin_amdgcn_mfma_f32_16x16x32_bf16(af[f], bf, acc[f][q], 0, 0, 0);
            }
        } else {
            #pragma unroll
            for (int q = 0; q < 2; ++q) {
                int nf = wid*2 + q;
                int pl = 1 + (nf >> 3), jr = (nf & 7)*16 + l15;
                short8 bf = *(const short8*)(tb2 + (pl*128 + jr)*32 + ((kg ^ swzkey(jr)) << 3));
                #pragma unroll
                for (int f = 0; f < 8; ++f)
                    acc[f][q] = __builtin_amdgcn_mfma_f32_16x16x32_bf16(af[f], bf, acc[f][q], 0, 0, 0);
            }
        }
    }
    ps0 += __shfl_xor(ps0, 1); ps0 += __shfl_xor(ps0, 2);
    ps1 += __shfl_xor(ps1, 1); ps1 += __shfl_xor(ps1, 2);
    if (grp == 0) {
        tacc += __shfl_xor(tacc, 1); tacc += __shfl_xor(tacc, 2);
        if (sub == 0) Tg[(size_t)(b*16 + kq)*128 + js] = tacc;
    }
    if (sub == 0) {
        float* tx = Txg + (((size_t)(b*16 + kq)*2 + grp)*2)*128;
        tx[js] = ps0;          // m = 1 + grp*2
        tx[128 + js] = ps1;    // m = 2 + grp*2
    }
    ushort* gp = Gpart + (size_t)(b*16 + kq)*81920;
    int nq = (grp == 0) ? 3 : 2;
    int nbase = (grp == 0) ? 0 : 384;
    #pragma unroll
    for (int f = 0; f < 8; ++f)
        #pragma unroll
        for (int q = 0; q < 3; ++q) {
            if (q < nq) {
                int n = nbase + (wid*nq + q)*16 + l15;
                uint2 pk;
                pk.x = (unsigned)f2bf(acc[f][q][0]) | ((unsigned)f2bf(acc[f][q][1]) << 16);
                pk.y = (unsigned)f2bf(acc[f][q][2]) | ((unsigned)f2bf(acc[f][q][3]) << 16);
                *(uint2*)(gp + ((size_t)(f*4 + kg)*640 + n)*4) = pk;
            }
        }
}

// ---- combine2: partial S over iq: parallel bf16-Gpart reduce + bilinear ----
__global__ __launch_bounds__(256) void combine2_kernel(
    const ushort* __restrict__ Gpart, const float* __restrict__ qkv_w,
    float* __restrict__ Spart2)
{
    __shared__ float Gm[32*128];   // 16 KB
    int blk = blockIdx.x;
    int iq = blk & 3, bm = blk >> 2;
    int b = bm / 5, m = bm - b*5;
    int t = threadIdx.x;
    for (int e = t; e < 1024; e += 256) {
        int qi = e >> 7, j = e & 127;
        float s0=0.f, s1=0.f, s2=0.f, s3=0.f;
        #pragma unroll
        for (int kq = 0; kq < 16; ++kq) {
            uint2 v = *(const uint2*)(Gpart + (size_t)(b*16 + kq)*81920
                        + ((size_t)(iq*8 + qi)*640 + m*128 + j)*4);
            s0 += bf2f((ushort)v.x); s1 += bf2f((ushort)(v.x >> 16));
            s2 += bf2f((ushort)v.y); s3 += bf2f((ushort)(v.y >> 16));
        }
        Gm[(qi*4 + 0)*128 + j] = s0;
        Gm[(qi*4 + 1)*128 + j] = s1;
        Gm[(qi*4 + 2)*128 + j] = s2;
        Gm[(qi*4 + 3)*128 + j] = s3;
    }
    __syncthreads();
    int c = t >> 1, jh = t & 1;
    float wkr[64];
    const float* wkp = qkv_w + (size_t)(128 + c)*128 + jh*64;
    #pragma unroll
    for (int q = 0; q < 16; ++q)
        *(float4*)&wkr[q*4] = ((const float4*)wkp)[q];
    const float* wqp = qkv_w + (size_t)c*128 + iq*32;
    float acc = 0.f;
    for (int i = 0; i < 32; ++i) {
        const float4* gr4 = (const float4*)(Gm + i*128 + jh*64);
        float val = 0.f;
        #pragma unroll
        for (int q = 0; q < 16; ++q) {
            float4 g4 = gr4[q];
            val += wkr[q*4+0]*g4.x + wkr[q*4+1]*g4.y
                 + wkr[q*4+2]*g4.z + wkr[q*4+3]*g4.w;
        }
        acc += wqp[i]*val;
    }
    acc += __shfl_xor(acc, 1);
    if (jh == 0) Spart2[((size_t)bm*4 + iq)*128 + c] = acc;
}

// ---- pw (softmax fused): attn from Spart2+bias, then PW_m = (proj.*attn_m)@Wv ----
__global__ __launch_bounds__(256) void pw_kernel(
    const float* __restrict__ Spart2, const float* __restrict__ Tg,
    const float* __restrict__ Txg, const float* __restrict__ qkv_w,
    const float* __restrict__ qkv_b, const float* __restrict__ proj_w,
    ushort* __restrict__ PW)
{
    __shared__ float attns[CC];
    __shared__ float Ts[5*128];
    __shared__ float wvs[32*CC];
    int blk = blockIdx.x;
    int b = blk / 5, m = blk % 5;
    int t = threadIdx.x;
    for (int i = t; i < 640; i += 256) {
        int v = i >> 7, cch = i & 127;
        float s = 0.f;
        if (v == 0) {
            for (int p = 0; p < 16; ++p) s += Tg[(size_t)(b*16 + p)*128 + cch];
        } else {
            int grp = (v - 1) >> 1, pi = (v - 1) & 1;
            for (int p = 0; p < 16; ++p)
                s += Txg[(((size_t)(b*16 + p)*2 + grp)*2 + pi)*128 + cch];
        }
        Ts[v*128 + cch] = s;
    }
    __syncthreads();
    if (t < 128) {
        int cc = t;
        float bq = qkv_b[cc], bk = qkv_b[128 + cc];
        const float* wqr = qkv_w + (size_t)cc*128;
        const float* wkr = qkv_w + (size_t)(128 + cc)*128;
        float t0d = 0.f;
        for (int j = 0; j < 128; ++j) t0d += wqr[j]*Ts[j];
        float s5[5];
        #pragma unroll
        for (int mm = 0; mm < 5; ++mm) {
            float km = 0.f;
            for (int j = 0; j < 128; ++j) km += wkr[j]*Ts[mm*128 + j];
            float ss = 0.f;
            #pragma unroll
            for (int iq = 0; iq < 4; ++iq)
                ss += Spart2[((size_t)(b*5 + mm)*4 + iq)*128 + cc];
            s5[mm] = ss + bq*km + bk*t0d + 4096.0f*bq*bk;
        }
        const float scale = 0.08838834764831845f;  // 1/sqrt(128)
        float mx = s5[0]*scale;
        #pragma unroll
        for (int mm = 1; mm < 5; ++mm) mx = fmaxf(mx, s5[mm]*scale);
        float e[5], tot = 0.f;
        #pragma unroll
        for (int mm = 0; mm < 5; ++mm) { e[mm] = expf(s5[mm]*scale - mx); tot += e[mm]; }
        attns[cc] = e[m]/tot;
    }
    int d = t >> 1, cb = (t & 1)*64;
    float acc[64];
    #pragma unroll
    for (int j = 0; j < 64; ++j) acc[j] = 0.f;
    for (int cc0 = 0; cc0 < CC; cc0 += 32) {
        __syncthreads();
        for (int idx = t; idx < 32*CC; idx += 256) {
            int row = idx >> 7, col = idx & 127;
            wvs[idx] = qkv_w[(2*CC + cc0 + row)*CC + col];
        }
        __syncthreads();
        for (int cl = 0; cl < 32; ++cl) {
            int c = cc0 + cl;
            float a = proj_w[d*CC + c]*attns[c];
            const float* wr = wvs + cl*CC + cb;
            #pragma unroll
            for (int j = 0; j < 64; ++j) acc[j] += a*wr[j];
        }
    }
    ushort* dst = PW + ((size_t)(b*5 + m) << 14) + d*CC + cb;
    #pragma unroll
    for (int j = 0; j < 64; ++j) dst[j] = f2bf(acc[j]);
}

// ---- phase B: Y[l][c_out] = sum_{m,c} tok[m][l][c]*PW_m[c_out][c] + cvec ----
// 64-l blocks (one h-row), 512 threads, single-barrier staging, 80 KB LDS.
__global__ __launch_bounds__(512) void y_kernel(
    const float* __restrict__ x, const ushort* __restrict__ gw,
    const ushort* __restrict__ PW, const float* __restrict__ cvec,
    float* __restrict__ out)
{
    __shared__ __align__(16) ushort tok[5*64*128];   // 80 KB; ylds overlays
    int t = threadIdx.x;
    int blk = blockIdx.x;
    int b = blk >> 6, h = blk & 63;
    int lane = t & 63, wave = t >> 6;
    int l15 = lane & 15, kg = lane >> 4;
    int swz = (l15 & 7) << 3;
    int lbase = (wave >> 2)*32;     // wave's l-half
    int cq = (wave & 3)*32;         // wave's c-quarter
    int c = t >> 2, r2 = t & 3;
    int r = r2 >> 1, half = r2 & 1;
    // ---- issue ALL loads upfront ----
    const ushort* gsrc = gw + ((size_t)(b*CC + c) << 12) + h*64 + r2*16;
    uint4 g0 = *(const uint4*)gsrc;
    uint4 g1 = *(const uint4*)(gsrc + 8);
    const float* xrow = x + ((size_t)(b*CC + c)*HH + 2*h + r)*WW + half*64;
    float4 xv[16];
    #pragma unroll
    for (int i = 0; i < 16; ++i) xv[i] = ((const float4*)xrow)[i];
    // ---- m0 writes (16 u16, l = r2*16..r2*16+15) ----
    {
        unsigned wd[8] = {g0.x,g0.y,g0.z,g0.w,g1.x,g1.y,g1.z,g1.w};
        #pragma unroll
        for (int k2 = 0; k2 < 8; ++k2) {
            int lp0 = r2*16 + 2*k2, lp1 = lp0 + 1;
            tok[lp0*128 + (c ^ ((lp0 & 7) << 3))] = (ushort)wd[k2];
            tok[lp1*128 + (c ^ ((lp1 & 7) << 3))] = (ushort)(wd[k2] >> 16);
        }
    }
    // ---- m1..4 writes: float4 i covers l = half*32 + 2i, 2i+1 ----
    {
        int mA = (1 + 2*r)*8192, mB = (2 + 2*r)*8192;
        int lb = half*32;
        #pragma unroll
        for (int i = 0; i < 16; ++i) {
            int lp0 = lb + 2*i, lp1 = lp0 + 1;
            int o0 = lp0*128 + (c ^ ((lp0 & 7) << 3));
            int o1 = lp1*128 + (c ^ ((lp1 & 7) << 3));
            tok[mA + o0] = f2bf(xv[i].x);
            tok[mB + o0] = f2bf(xv[i].y);
            tok[mA + o1] = f2bf(xv[i].z);
            tok[mB + o1] = f2bf(xv[i].w);
        }
    }
    __syncthreads();
    f32x4 acc[2][2] = {};
    #pragma unroll
    for (int m = 0; m < 5; ++m) {
        const ushort* pwb = PW + ((size_t)(b*5 + m) << 14)
                          + ((cq + l15) << 7) + (kg << 3);
        #pragma unroll
        for (int kt = 0; kt < 4; ++kt) {
            int ko = (kt*32 + kg*8) ^ swz;
            short8 a0 = *(const short8*)(tok + m*8192 + (lbase + l15     )*128 + ko);
            short8 a1 = *(const short8*)(tok + m*8192 + (lbase + 16 + l15)*128 + ko);
            short8 b0 = *(const short8*)(pwb + kt*32);
            short8 b1 = *(const short8*)(pwb + (16 << 7) + kt*32);
            acc[0][0] = __builtin_amdgcn_mfma_f32_16x16x32_bf16(a0, b0, acc[0][0], 0, 0, 0);
            acc[0][1] = __builtin_amdgcn_mfma_f32_16x16x32_bf16(a0, b1, acc[0][1], 0, 0, 0);
            acc[1][0] = __builtin_amdgcn_mfma_f32_16x16x32_bf16(a1, b0, acc[1][0], 0, 0, 0);
            acc[1][1] = __builtin_amdgcn_mfma_f32_16x16x32_bf16(a1, b1, acc[1][1], 0, 0, 0);
        }
    }
    __syncthreads();
    float* ylds = (float*)tok;   // [128][68] = 34.8 KB
    #pragma unroll
    for (int mt = 0; mt < 2; ++mt)
        #pragma unroll
        for (int ntl = 0; ntl < 2; ++ntl) {
            int cc = cq + ntl*16 + l15;
            float cv = cvec[cc];
            #pragma unroll
            for (int rr = 0; rr < 4; ++rr) {
                int l = lbase + mt*16 + kg*4 + rr;
                ylds[cc*68 + l] = acc[mt][ntl][rr] + cv;
            }
        }
    __syncthreads();
    int c2 = t >> 2, q = t & 3;
    float* ob = out + ((size_t)(b*CC + c2) << 12) + h*64 + q*16;
    const float* yr = ylds + c2*68 + q*16;
    #pragma unroll
    for (int j = 0; j < 4; ++j)
        ((float4*)ob)[j] = ((const float4*)yr)[j];
}

extern "C" void kernel_launch(void* const* d_in, const int* in_sizes, int n_in,
                              void* d_out, int out_size, void* d_ws, size_t ws_size,
                              hipStream_t stream) {
    const float* x        = (const float*)d_in[0];
    const float* bn_gamma = (const float*)d_in[1];
    const float* bn_beta  = (const float*)d_in[2];
    const float* bn_mean  = (const float*)d_in[3];
    const float* bn_var   = (const float*)d_in[4];
    const float* dw_w     = (const float*)d_in[5];
    const float* dw_b     = (const float*)d_in[6];
    const float* qkv_w    = (const float*)d_in[7];
    const float* qkv_b    = (const float*)d_in[8];
    const float* proj_w   = (const float*)d_in[9];
    const float* proj_b   = (const float*)d_in[10];
    float* out = (float*)d_out;

    char* w = (char*)d_ws;
    ushort* gw     = (ushort*)w; w += (size_t)BB*CC*LL*2;          // 16.8 MB
    ushort* PW     = (ushort*)w; w += (size_t)BB*5*CC*CC*2;        // 2.6 MB
    ushort* Gpart  = (ushort*)w; w += (size_t)BB*16*81920*2;       // 41.9 MB (bf16)
    float*  Tg     = (float*)w;  w += (size_t)BB*16*128*4;         // 131 KB
    float*  Txg    = (float*)w;  w += (size_t)BB*16*2*2*128*4;     // 524 KB
    float*  Spart2 = (float*)w;  w += (size_t)BB*5*4*128*4;        // 164 KB
    float*  cvec   = (float*)w;  w += (size_t)CC*4;

    prep_cvec<<<1, 128, 0, stream>>>(qkv_b, proj_w, proj_b, cvec);
    guide_kernel<<<dim3(BB*CC, 2), 256, 0, stream>>>(
        x, bn_gamma, bn_beta, bn_mean, bn_var, dw_w, dw_b, gw);
    gram_kernel<<<512, 512, 0, stream>>>(x, gw, Gpart, Tg, Txg);
    combine2_kernel<<<BB*5*4, 256, 0, stream>>>(Gpart, qkv_w, Spart2);
    pw_kernel<<<BB*5, 256, 0, stream>>>(Spart2, Tg, Txg, qkv_w, qkv_b, proj_w, PW);
    y_kernel<<<BB*64, 512, 0, stream>>>(x, gw, PW, cvec, out);
}

// Round 16
// 195.596 us; speedup vs baseline: 1.2588x; 1.2588x over previous
//
#include <hip/hip_runtime.h>
#include <math.h>

#define BB 16
#define CC 128
#define HH 128
#define WW 128
#define LL 4096

typedef short short8 __attribute__((ext_vector_type(8)));
typedef float f32x4 __attribute__((ext_vector_type(4)));

__device__ __forceinline__ ushort f2bf(float f) {
    union { float f; unsigned u; } un; un.f = f;
    unsigned u = un.u;
    u += 0x7fffu + ((u >> 16) & 1u);   // RNE
    return (ushort)(u >> 16);
}
__device__ __forceinline__ float bf2f(ushort h) {
    union { unsigned u; float f; } un; un.u = ((unsigned)h) << 16;
    return un.f;
}
__device__ __forceinline__ float fast_gelu(float xv) {
    float x2 = xv*xv;
    float arg = xv*(-2.3022100f - 0.1029436f*x2);
    float e = exp2f(arg);
    return xv*__builtin_amdgcn_rcpf(1.f + e);
}
__device__ __forceinline__ int swzkey(int r) { return (r & 3) ^ ((r >> 2) & 3); }

// ---- prep: cvec = proj@bv + proj_b ----
__global__ __launch_bounds__(128) void prep_cvec(
    const float* __restrict__ qkv_b, const float* __restrict__ proj_w,
    const float* __restrict__ proj_b, float* __restrict__ cvec)
{
    int t = threadIdx.x;
    float s = proj_b[t];
    const float* pr = proj_w + t*CC;
    const float* bv = qkv_b + 2*CC;
    for (int c = 0; c < CC; ++c) s += pr[c]*bv[c];
    cvec[t] = s;
}

// ---- guide = dwconv7x7_s2(gelu(bn(x))), bf16 out [b][c][64*64]  (R12 form) ----
__global__ __launch_bounds__(256) void guide_kernel(
    const float* __restrict__ x, const float* __restrict__ gamma,
    const float* __restrict__ beta, const float* __restrict__ mean,
    const float* __restrict__ var, const float* __restrict__ dww,
    const float* __restrict__ dwb, ushort* __restrict__ gw)
{
    int bc = blockIdx.x;
    int b = bc >> 7, c = bc & 127;
    int ty = blockIdx.y;
    __shared__ __align__(16) float g[69*144];
    int t = threadIdx.x;
    float wreg[49];
    #pragma unroll
    for (int k = 0; k < 49; ++k) wreg[k] = dww[c*49 + k];
    float bias = dwb[c];
    float scl = gamma[c] * rsqrtf(var[c] + 1e-5f);
    float sft = beta[c] - mean[c]*scl;
    const float* xb = x + (size_t)(b*CC + c)*HH*WW;
    int ihbase = 64*ty - 3;
    #pragma unroll
    for (int k = 0; k < 9; ++k) {
        int idx = k*256 + t;
        if (idx < 69*32) {
            int row = idx >> 5, ch = idx & 31;
            int ih = ihbase + row;
            float4 v4 = {0.f, 0.f, 0.f, 0.f};
            if ((unsigned)ih < 128u) {
                float4 xv = *(const float4*)(xb + ih*WW + 4*ch);
                v4.x = fast_gelu(xv.x*scl + sft);
                v4.y = fast_gelu(xv.y*scl + sft);
                v4.z = fast_gelu(xv.z*scl + sft);
                v4.w = fast_gelu(xv.w*scl + sft);
            }
            int f = (row >> 2) & 3;
            *(float4*)(g + row*144 + 4*((ch + 1) ^ f)) = v4;
        }
    }
    if (t < 138) {
        int row = t >> 1;
        int lc = (t & 1) ? 33 : 0;
        int f = (row >> 2) & 3;
        float4 z4 = {0.f, 0.f, 0.f, 0.f};
        *(float4*)(g + row*144 + 4*(lc ^ f)) = z4;
    }
    __syncthreads();
    int vg = t >> 4, owg = t & 15;
    float acc[2][4];
    #pragma unroll
    for (int v = 0; v < 2; ++v)
        #pragma unroll
        for (int hh = 0; hh < 4; ++hh) acc[v][hh] = bias;
    #pragma unroll
    for (int j = 0; j < 9; ++j) {
        int rr = 4*vg + j;
        int f = (rr >> 2) & 3;
        const float* grow = g + rr*144;
        float win[16];
        #pragma unroll
        for (int i = 0; i < 4; ++i) {
            float4 w4 = *(const float4*)(grow + 4*(((2*owg + i) ^ f)));
            win[4*i+0] = w4.x; win[4*i+1] = w4.y;
            win[4*i+2] = w4.z; win[4*i+3] = w4.w;
        }
        #pragma unroll
        for (int v = 0; v < 2; ++v) {
            int kh = j - 2*v;
            if (kh >= 0 && kh <= 6) {
                #pragma unroll
                for (int hh = 0; hh < 4; ++hh)
                    #pragma unroll
                    for (int kw = 0; kw < 7; ++kw)
                        acc[v][hh] += wreg[kh*7 + kw] * win[2*hh + kw + 1];
            }
        }
    }
    int orbase = 32*ty + 2*vg;
    ushort* gdst = gw + ((size_t)(b*CC + c) << 12);
    #pragma unroll
    for (int v = 0; v < 2; ++v) {
        uint2 pk;
        pk.x = (unsigned)f2bf(acc[v][0]) | ((unsigned)f2bf(acc[v][1]) << 16);
        pk.y = (unsigned)f2bf(acc[v][2]) | ((unsigned)f2bf(acc[v][3]) << 16);
        *(uint2*)(gdst + (orbase + v)*64 + 4*owg) = pk;
    }
}

// ---- Gram_m[i,j] = sum_l t0[i,l]*t_m[j,l]; kq=16; bf16-packed output + T partials ----
__global__ __launch_bounds__(512) void gram_kernel(
    const float* __restrict__ x, const ushort* __restrict__ gw,
    ushort* __restrict__ Gpart, float* __restrict__ Tg, float* __restrict__ Txg)
{
    __shared__ __align__(16) ushort tokb[2*3*128*32];
    int t = threadIdx.x;
    int blk = blockIdx.x;
    int b = blk >> 5, kq = (blk >> 1) & 15, grp = blk & 1;
    int lane = t & 63, wid = t >> 6;
    int l15 = lane & 15, kg = lane >> 4;
    int js = t >> 2, sub = t & 3;
    int keyj = swzkey(js);
    const float* xrow0 = x + ((size_t)(b*CC + js)*HH + grp)*WW;
    const ushort* gwrow = gw + ((size_t)(b*CC + js) << 12);
    f32x4 acc[8][3];
    #pragma unroll
    for (int i = 0; i < 8; ++i)
        #pragma unroll
        for (int q = 0; q < 3; ++q) acc[i][q] = (f32x4){0.f,0.f,0.f,0.f};
    float tacc = 0.f, ps0 = 0.f, ps1 = 0.f;
    int H0 = kq*4;
    float4 xa, xbv, xc, xd;
    uint4 gr;
    {
        const float* xp = xrow0 + (2*H0)*WW + sub*16;
        xa = *(const float4*)(xp);
        xbv = *(const float4*)(xp + 4);
        xc = *(const float4*)(xp + 8);
        xd = *(const float4*)(xp + 12);
        gr = *(const uint4*)(gwrow + H0*64 + sub*8);
    }
    for (int s = 0; s < 8; ++s) {
        int cur = s & 1;
        ushort* tb = tokb + cur*(3*128*32);
        if (grp == 0) {
            tacc += bf2f((ushort)gr.x) + bf2f((ushort)(gr.x >> 16))
                  + bf2f((ushort)gr.y) + bf2f((ushort)(gr.y >> 16))
                  + bf2f((ushort)gr.z) + bf2f((ushort)(gr.z >> 16))
                  + bf2f((ushort)gr.w) + bf2f((ushort)(gr.w >> 16));
        }
        ps0 += xa.x + xa.z + xbv.x + xbv.z + xc.x + xc.z + xd.x + xd.z;
        ps1 += xa.y + xa.w + xbv.y + xbv.w + xc.y + xc.w + xd.y + xd.w;
        {
            unsigned lo0 = (unsigned)f2bf(xa.x) | ((unsigned)f2bf(xa.z) << 16);
            unsigned lo1 = (unsigned)f2bf(xbv.x) | ((unsigned)f2bf(xbv.z) << 16);
            unsigned lo2 = (unsigned)f2bf(xc.x) | ((unsigned)f2bf(xc.z) << 16);
            unsigned lo3 = (unsigned)f2bf(xd.x) | ((unsigned)f2bf(xd.z) << 16);
            unsigned hi0 = (unsigned)f2bf(xa.y) | ((unsigned)f2bf(xa.w) << 16);
            unsigned hi1 = (unsigned)f2bf(xbv.y) | ((unsigned)f2bf(xbv.w) << 16);
            unsigned hi2 = (unsigned)f2bf(xc.y) | ((unsigned)f2bf(xc.w) << 16);
            unsigned hi3 = (unsigned)f2bf(xd.y) | ((unsigned)f2bf(xd.w) << 16);
            uint4 lov = {lo0, lo1, lo2, lo3};
            uint4 hiv = {hi0, hi1, hi2, hi3};
            int chs = (sub ^ keyj) << 3;
            *(uint4*)(tb + (1*128 + js)*32 + chs) = lov;
            *(uint4*)(tb + (2*128 + js)*32 + chs) = hiv;
            *(uint4*)(tb + (0*128 + js)*32 + chs) = gr;
        }
        if (s < 7) {
            int sn = s + 1;
            int h = H0 + (sn >> 1), whalf = sn & 1;
            const float* xp = xrow0 + (2*h)*WW + whalf*64 + sub*16;
            xa = *(const float4*)(xp);
            xbv = *(const float4*)(xp + 4);
            xc = *(const float4*)(xp + 8);
            xd = *(const float4*)(xp + 12);
            gr = *(const uint4*)(gwrow + h*64 + whalf*32 + sub*8);
        }
        __syncthreads();
        const ushort* tb2 = tokb + cur*(3*128*32);
        short8 af[8];
        #pragma unroll
        for (int f = 0; f < 8; ++f) {
            int row = f*16 + l15;
            af[f] = *(const short8*)(tb2 + row*32 + ((kg ^ swzkey(row)) << 3));
        }
        if (grp == 0) {
            #pragma unroll
            for (int q = 0; q < 3; ++q) {
                int nf = wid*3 + q;
                int pl = nf >> 3, jr = (nf & 7)*16 + l15;
                short8 bf = *(const short8*)(tb2 + (pl*128 + jr)*32 + ((kg ^ swzkey(jr)) << 3));
                #pragma unroll
                for (int f = 0; f < 8; ++f)
                    acc[f][q] = __builtin_amdgcn_mfma_f32_16x16x32_bf16(af[f], bf, acc[f][q], 0, 0, 0);
            }
        } else {
            #pragma unroll
            for (int q = 0; q < 2; ++q) {
                int nf = wid*2 + q;
                int pl = 1 + (nf >> 3), jr = (nf & 7)*16 + l15;
                short8 bf = *(const short8*)(tb2 + (pl*128 + jr)*32 + ((kg ^ swzkey(jr)) << 3));
                #pragma unroll
                for (int f = 0; f < 8; ++f)
                    acc[f][q] = __builtin_amdgcn_mfma_f32_16x16x32_bf16(af[f], bf, acc[f][q], 0, 0, 0);
            }
        }
    }
    ps0 += __shfl_xor(ps0, 1); ps0 += __shfl_xor(ps0, 2);
    ps1 += __shfl_xor(ps1, 1); ps1 += __shfl_xor(ps1, 2);
    if (grp == 0) {
        tacc += __shfl_xor(tacc, 1); tacc += __shfl_xor(tacc, 2);
        if (sub == 0) Tg[(size_t)(b*16 + kq)*128 + js] = tacc;
    }
    if (sub == 0) {
        float* tx = Txg + (((size_t)(b*16 + kq)*2 + grp)*2)*128;
        tx[js] = ps0;          // m = 1 + grp*2
        tx[128 + js] = ps1;    // m = 2 + grp*2
    }
    ushort* gp = Gpart + (size_t)(b*16 + kq)*81920;
    int nq = (grp == 0) ? 3 : 2;
    int nbase = (grp == 0) ? 0 : 384;
    #pragma unroll
    for (int f = 0; f < 8; ++f)
        #pragma unroll
        for (int q = 0; q < 3; ++q) {
            if (q < nq) {
                int n = nbase + (wid*nq + q)*16 + l15;
                uint2 pk;
                pk.x = (unsigned)f2bf(acc[f][q][0]) | ((unsigned)f2bf(acc[f][q][1]) << 16);
                pk.y = (unsigned)f2bf(acc[f][q][2]) | ((unsigned)f2bf(acc[f][q][3]) << 16);
                *(uint2*)(gp + ((size_t)(f*4 + kg)*640 + n)*4) = pk;
            }
        }
}

// ---- combine2: partial S over iq: parallel bf16-Gpart reduce + bilinear ----
__global__ __launch_bounds__(256) void combine2_kernel(
    const ushort* __restrict__ Gpart, const float* __restrict__ qkv_w,
    float* __restrict__ Spart2)
{
    __shared__ float Gm[32*128];   // 16 KB
    int blk = blockIdx.x;
    int iq = blk & 3, bm = blk >> 2;
    int b = bm / 5, m = bm - b*5;
    int t = threadIdx.x;
    for (int e = t; e < 1024; e += 256) {
        int qi = e >> 7, j = e & 127;
        float s0=0.f, s1=0.f, s2=0.f, s3=0.f;
        #pragma unroll
        for (int kq = 0; kq < 16; ++kq) {
            uint2 v = *(const uint2*)(Gpart + (size_t)(b*16 + kq)*81920
                        + ((size_t)(iq*8 + qi)*640 + m*128 + j)*4);
            s0 += bf2f((ushort)v.x); s1 += bf2f((ushort)(v.x >> 16));
            s2 += bf2f((ushort)v.y); s3 += bf2f((ushort)(v.y >> 16));
        }
        Gm[(qi*4 + 0)*128 + j] = s0;
        Gm[(qi*4 + 1)*128 + j] = s1;
        Gm[(qi*4 + 2)*128 + j] = s2;
        Gm[(qi*4 + 3)*128 + j] = s3;
    }
    __syncthreads();
    int c = t >> 1, jh = t & 1;
    float wkr[64];
    const float* wkp = qkv_w + (size_t)(128 + c)*128 + jh*64;
    #pragma unroll
    for (int q = 0; q < 16; ++q)
        *(float4*)&wkr[q*4] = ((const float4*)wkp)[q];
    const float* wqp = qkv_w + (size_t)c*128 + iq*32;
    float acc = 0.f;
    for (int i = 0; i < 32; ++i) {
        const float4* gr4 = (const float4*)(Gm + i*128 + jh*64);
        float val = 0.f;
        #pragma unroll
        for (int q = 0; q < 16; ++q) {
            float4 g4 = gr4[q];
            val += wkr[q*4+0]*g4.x + wkr[q*4+1]*g4.y
                 + wkr[q*4+2]*g4.z + wkr[q*4+3]*g4.w;
        }
        acc += wqp[i]*val;
    }
    acc += __shfl_xor(acc, 1);
    if (jh == 0) Spart2[((size_t)bm*4 + iq)*128 + c] = acc;
}

// ---- softmax + exact bias terms (separate small kernel) ----
__global__ __launch_bounds__(128) void softmax_attn(
    const float* __restrict__ Spart2, const float* __restrict__ Tg,
    const float* __restrict__ Txg, const float* __restrict__ qkv_w,
    const float* __restrict__ qkv_b, float* __restrict__ attn)
{
    __shared__ float Ts[5*128];
    int b = blockIdx.x, t = threadIdx.x;
    #pragma unroll
    for (int v = 0; v < 5; ++v) {
        float s = 0.f;
        if (v == 0) {
            for (int p = 0; p < 16; ++p) s += Tg[(size_t)(b*16 + p)*128 + t];
        } else {
            int grp = (v - 1) >> 1, pi = (v - 1) & 1;
            for (int p = 0; p < 16; ++p)
                s += Txg[(((size_t)(b*16 + p)*2 + grp)*2 + pi)*128 + t];
        }
        Ts[v*128 + t] = s;
    }
    __syncthreads();
    int c = t;
    float bq = qkv_b[c], bk = qkv_b[128 + c];
    const float* wqr = qkv_w + (size_t)c*128;
    const float* wkr = qkv_w + (size_t)(128 + c)*128;
    float t0d = 0.f;
    for (int j = 0; j < 128; ++j) t0d += wqr[j]*Ts[j];
    float s5[5];
    #pragma unroll
    for (int m = 0; m < 5; ++m) {
        float km = 0.f;
        for (int j = 0; j < 128; ++j) km += wkr[j]*Ts[m*128 + j];
        float ss = 0.f;
        #pragma unroll
        for (int iq = 0; iq < 4; ++iq)
            ss += Spart2[((size_t)(b*5 + m)*4 + iq)*128 + c];
        s5[m] = ss + bq*km + bk*t0d + 4096.0f*bq*bk;
    }
    const float scale = 0.08838834764831845f;  // 1/sqrt(128)
    float mx = s5[0]*scale;
    #pragma unroll
    for (int m = 1; m < 5; ++m) mx = fmaxf(mx, s5[m]*scale);
    float e[5], tot = 0.f;
    #pragma unroll
    for (int m = 0; m < 5; ++m) { e[m] = expf(s5[m]*scale - mx); tot += e[m]; }
    float inv = 1.f/tot;
    #pragma unroll
    for (int m = 0; m < 5; ++m) attn[(size_t)(b*128 + c)*5 + m] = e[m]*inv;
}

// ---- pw: PW_m[b][:, jq*32..+31] = (proj .* attn_m) @ Wv-slab; grid 320 ----
__global__ __launch_bounds__(256) void pw_kernel(
    const float* __restrict__ qkv_w, const float* __restrict__ proj_w,
    const float* __restrict__ attn, ushort* __restrict__ PW)
{
    __shared__ float attns[CC];
    __shared__ float wvs[128*33];   // 16.9 KB, padded
    int blk = blockIdx.x;
    int jq = blk & 3, bm = blk >> 2;
    int b = bm / 5, m = bm - b*5;
    int t = threadIdx.x;
    if (t < 128) attns[t] = attn[(size_t)(b*CC + t)*5 + m];
    for (int idx = t; idx < 128*32; idx += 256) {
        int row = idx >> 5, col = idx & 31;
        wvs[row*33 + col] = qkv_w[(size_t)(2*CC + row)*CC + jq*32 + col];
    }
    __syncthreads();
    int d = t >> 1, jh = t & 1;
    float acc[16];
    #pragma unroll
    for (int j = 0; j < 16; ++j) acc[j] = 0.f;
    const float* pr = proj_w + (size_t)d*CC;
    for (int c = 0; c < 128; ++c) {
        float a = pr[c]*attns[c];
        const float* wr = wvs + c*33 + jh*16;
        #pragma unroll
        for (int j = 0; j < 16; ++j) acc[j] += a*wr[j];
    }
    ushort* dst = PW + ((size_t)(b*5 + m) << 14) + (size_t)d*CC + jq*32 + jh*16;
    #pragma unroll
    for (int j = 0; j < 16; ++j) dst[j] = f2bf(acc[j]);
}

// ---- phase B: Y[l][c_out] = sum_{m,c} tok[m][l][c]*PW_m[c_out][c] + cvec ----
// 64-l blocks (one h-row), 512 threads, single-barrier staging, 80 KB LDS.
__global__ __launch_bounds__(512) void y_kernel(
    const float* __restrict__ x, const ushort* __restrict__ gw,
    const ushort* __restrict__ PW, const float* __restrict__ cvec,
    float* __restrict__ out)
{
    __shared__ __align__(16) ushort tok[5*64*128];   // 80 KB; ylds overlays
    int t = threadIdx.x;
    int blk = blockIdx.x;
    int b = blk >> 6, h = blk & 63;
    int lane = t & 63, wave = t >> 6;
    int l15 = lane & 15, kg = lane >> 4;
    int swz = (l15 & 7) << 3;
    int lbase = (wave >> 2)*32;
    int cq = (wave & 3)*32;
    int c = t >> 2, r2 = t & 3;
    int r = r2 >> 1, half = r2 & 1;
    const ushort* gsrc = gw + ((size_t)(b*CC + c) << 12) + h*64 + r2*16;
    uint4 g0 = *(const uint4*)gsrc;
    uint4 g1 = *(const uint4*)(gsrc + 8);
    const float* xrow = x + ((size_t)(b*CC + c)*HH + 2*h + r)*WW + half*64;
    float4 xv[16];
    #pragma unroll
    for (int i = 0; i < 16; ++i) xv[i] = ((const float4*)xrow)[i];
    {
        unsigned wd[8] = {g0.x,g0.y,g0.z,g0.w,g1.x,g1.y,g1.z,g1.w};
        #pragma unroll
        for (int k2 = 0; k2 < 8; ++k2) {
            int lp0 = r2*16 + 2*k2, lp1 = lp0 + 1;
            tok[lp0*128 + (c ^ ((lp0 & 7) << 3))] = (ushort)wd[k2];
            tok[lp1*128 + (c ^ ((lp1 & 7) << 3))] = (ushort)(wd[k2] >> 16);
        }
    }
    {
        int mA = (1 + 2*r)*8192, mB = (2 + 2*r)*8192;
        int lb = half*32;
        #pragma unroll
        for (int i = 0; i < 16; ++i) {
            int lp0 = lb + 2*i, lp1 = lp0 + 1;
            int o0 = lp0*128 + (c ^ ((lp0 & 7) << 3));
            int o1 = lp1*128 + (c ^ ((lp1 & 7) << 3));
            tok[mA + o0] = f2bf(xv[i].x);
            tok[mB + o0] = f2bf(xv[i].y);
            tok[mA + o1] = f2bf(xv[i].z);
            tok[mB + o1] = f2bf(xv[i].w);
        }
    }
    __syncthreads();
    f32x4 acc[2][2] = {};
    #pragma unroll
    for (int m = 0; m < 5; ++m) {
        const ushort* pwb = PW + ((size_t)(b*5 + m) << 14)
                          + ((cq + l15) << 7) + (kg << 3);
        #pragma unroll
        for (int kt = 0; kt < 4; ++kt) {
            int ko = (kt*32 + kg*8) ^ swz;
            short8 a0 = *(const short8*)(tok + m*8192 + (lbase + l15     )*128 + ko);
            short8 a1 = *(const short8*)(tok + m*8192 + (lbase + 16 + l15)*128 + ko);
            short8 b0 = *(const short8*)(pwb + kt*32);
            short8 b1 = *(const short8*)(pwb + (16 << 7) + kt*32);
            acc[0][0] = __builtin_amdgcn_mfma_f32_16x16x32_bf16(a0, b0, acc[0][0], 0, 0, 0);
            acc[0][1] = __builtin_amdgcn_mfma_f32_16x16x32_bf16(a0, b1, acc[0][1], 0, 0, 0);
            acc[1][0] = __builtin_amdgcn_mfma_f32_16x16x32_bf16(a1, b0, acc[1][0], 0, 0, 0);
            acc[1][1] = __builtin_amdgcn_mfma_f32_16x16x32_bf16(a1, b1, acc[1][1], 0, 0, 0);
        }
    }
    __syncthreads();
    float* ylds = (float*)tok;   // [128][68]
    #pragma unroll
    for (int mt = 0; mt < 2; ++mt)
        #pragma unroll
        for (int ntl = 0; ntl < 2; ++ntl) {
            int cc = cq + ntl*16 + l15;
            float cv = cvec[cc];
            #pragma unroll
            for (int rr = 0; rr < 4; ++rr) {
                int l = lbase + mt*16 + kg*4 + rr;
                ylds[cc*68 + l] = acc[mt][ntl][rr] + cv;
            }
        }
    __syncthreads();
    int c2 = t >> 2, q = t & 3;
    float* ob = out + ((size_t)(b*CC + c2) << 12) + h*64 + q*16;
    const float* yr = ylds + c2*68 + q*16;
    #pragma unroll
    for (int j = 0; j < 4; ++j)
        ((float4*)ob)[j] = ((const float4*)yr)[j];
}

extern "C" void kernel_launch(void* const* d_in, const int* in_sizes, int n_in,
                              void* d_out, int out_size, void* d_ws, size_t ws_size,
                              hipStream_t stream) {
    const float* x        = (const float*)d_in[0];
    const float* bn_gamma = (const float*)d_in[1];
    const float* bn_beta  = (const float*)d_in[2];
    const float* bn_mean  = (const float*)d_in[3];
    const float* bn_var   = (const float*)d_in[4];
    const float* dw_w     = (const float*)d_in[5];
    const float* dw_b     = (const float*)d_in[6];
    const float* qkv_w    = (const float*)d_in[7];
    const float* qkv_b    = (const float*)d_in[8];
    const float* proj_w   = (const float*)d_in[9];
    const float* proj_b   = (const float*)d_in[10];
    float* out = (float*)d_out;

    char* w = (char*)d_ws;
    ushort* gw     = (ushort*)w; w += (size_t)BB*CC*LL*2;          // 16.8 MB
    ushort* PW     = (ushort*)w; w += (size_t)BB*5*CC*CC*2;        // 2.6 MB
    ushort* Gpart  = (ushort*)w; w += (size_t)BB*16*81920*2;       // 41.9 MB (bf16)
    float*  Tg     = (float*)w;  w += (size_t)BB*16*128*4;         // 131 KB
    float*  Txg    = (float*)w;  w += (size_t)BB*16*2*2*128*4;     // 524 KB
    float*  Spart2 = (float*)w;  w += (size_t)BB*5*4*128*4;        // 164 KB
    float*  attn   = (float*)w;  w += (size_t)BB*CC*5*4;           // 40 KB
    float*  cvec   = (float*)w;  w += (size_t)CC*4;

    prep_cvec<<<1, 128, 0, stream>>>(qkv_b, proj_w, proj_b, cvec);
    guide_kernel<<<dim3(BB*CC, 2), 256, 0, stream>>>(
        x, bn_gamma, bn_beta, bn_mean, bn_var, dw_w, dw_b, gw);
    gram_kernel<<<512, 512, 0, stream>>>(x, gw, Gpart, Tg, Txg);
    combine2_kernel<<<BB*5*4, 256, 0, stream>>>(Gpart, qkv_w, Spart2);
    softmax_attn<<<BB, 128, 0, stream>>>(Spart2, Tg, Txg, qkv_w, qkv_b, attn);
    pw_kernel<<<BB*5*4, 256, 0, stream>>>(qkv_w, proj_w, attn, PW);
    y_kernel<<<BB*64, 512, 0, stream>>>(x, gw, PW, cvec, out);
}

// Round 17
// 195.015 us; speedup vs baseline: 1.2625x; 1.0030x over previous
//
#include <hip/hip_runtime.h>
#include <math.h>

#define BB 16
#define CC 128
#define HH 128
#define WW 128
#define LL 4096

typedef short short8 __attribute__((ext_vector_type(8)));
typedef float f32x4 __attribute__((ext_vector_type(4)));

__device__ __forceinline__ ushort f2bf(float f) {
    union { float f; unsigned u; } un; un.f = f;
    unsigned u = un.u;
    u += 0x7fffu + ((u >> 16) & 1u);   // RNE
    return (ushort)(u >> 16);
}
__device__ __forceinline__ float bf2f(ushort h) {
    union { unsigned u; float f; } un; un.u = ((unsigned)h) << 16;
    return un.f;
}
__device__ __forceinline__ float fast_gelu(float xv) {
    float x2 = xv*xv;
    float arg = xv*(-2.3022100f - 0.1029436f*x2);
    float e = exp2f(arg);
    return xv*__builtin_amdgcn_rcpf(1.f + e);
}
__device__ __forceinline__ int swzkey(int r) { return (r & 3) ^ ((r >> 2) & 3); }

// ---- guide = dwconv7x7_s2(gelu(bn(x))), bf16 out [b][c][64*64] ----
// ty=4 tiles: 16 out rows each, 37 staged rows, LDS 21.3 KB -> 7 blocks/CU.
__global__ __launch_bounds__(256) void guide_kernel(
    const float* __restrict__ x, const float* __restrict__ gamma,
    const float* __restrict__ beta, const float* __restrict__ mean,
    const float* __restrict__ var, const float* __restrict__ dww,
    const float* __restrict__ dwb, ushort* __restrict__ gw)
{
    int bc = blockIdx.x;
    int b = bc >> 7, c = bc & 127;
    int ty = blockIdx.y;                       // 0..3
    __shared__ __align__(16) float g[37*144];  // 21.3 KB
    int t = threadIdx.x;
    float wreg[49];
    #pragma unroll
    for (int k = 0; k < 49; ++k) wreg[k] = dww[c*49 + k];
    float bias = dwb[c];
    float scl = gamma[c] * rsqrtf(var[c] + 1e-5f);
    float sft = beta[c] - mean[c]*scl;
    const float* xb = x + (size_t)(b*CC + c)*HH*WW;
    int ihbase = 32*ty - 3;
    #pragma unroll
    for (int k = 0; k < 5; ++k) {
        int idx = k*256 + t;
        if (idx < 37*32) {
            int row = idx >> 5, ch = idx & 31;
            int ih = ihbase + row;
            float4 v4 = {0.f, 0.f, 0.f, 0.f};
            if ((unsigned)ih < 128u) {
                float4 xv = *(const float4*)(xb + ih*WW + 4*ch);
                v4.x = fast_gelu(xv.x*scl + sft);
                v4.y = fast_gelu(xv.y*scl + sft);
                v4.z = fast_gelu(xv.z*scl + sft);
                v4.w = fast_gelu(xv.w*scl + sft);
            }
            int f = (row >> 2) & 3;
            *(float4*)(g + row*144 + 4*((ch + 1) ^ f)) = v4;
        }
    }
    if (t < 74) {
        int row = t >> 1;
        int lc = (t & 1) ? 33 : 0;
        int f = (row >> 2) & 3;
        float4 z4 = {0.f, 0.f, 0.f, 0.f};
        *(float4*)(g + row*144 + 4*(lc ^ f)) = z4;
    }
    __syncthreads();
    int vg = t >> 4, owg = t & 15;      // out row ty*16+vg, cols 4*owg..+3
    float a0 = bias, a1 = bias, a2 = bias, a3 = bias;
    #pragma unroll
    for (int kh = 0; kh < 7; ++kh) {
        int rr = 2*vg + kh;
        int f = (rr >> 2) & 3;
        const float* grow = g + rr*144;
        float win[16];
        #pragma unroll
        for (int i = 0; i < 4; ++i) {
            float4 w4 = *(const float4*)(grow + 4*(((2*owg + i) ^ f)));
            win[4*i+0] = w4.x; win[4*i+1] = w4.y;
            win[4*i+2] = w4.z; win[4*i+3] = w4.w;
        }
        #pragma unroll
        for (int kw = 0; kw < 7; ++kw) {
            float wv = wreg[kh*7 + kw];
            a0 += wv * win[kw + 1];
            a1 += wv * win[kw + 3];
            a2 += wv * win[kw + 5];
            a3 += wv * win[kw + 7];
        }
    }
    uint2 pk;
    pk.x = (unsigned)f2bf(a0) | ((unsigned)f2bf(a1) << 16);
    pk.y = (unsigned)f2bf(a2) | ((unsigned)f2bf(a3) << 16);
    *(uint2*)(gw + ((size_t)(b*CC + c) << 12) + (ty*16 + vg)*64 + 4*owg) = pk;
}

// ---- Gram_m[i,j] = sum_l t0[i,l]*t_m[j,l]; kq=16; bf16-packed output + T partials ----
__global__ __launch_bounds__(512) void gram_kernel(
    const float* __restrict__ x, const ushort* __restrict__ gw,
    ushort* __restrict__ Gpart, float* __restrict__ Tg, float* __restrict__ Txg)
{
    __shared__ __align__(16) ushort tokb[2*3*128*32];
    int t = threadIdx.x;
    int blk = blockIdx.x;
    int b = blk >> 5, kq = (blk >> 1) & 15, grp = blk & 1;
    int lane = t & 63, wid = t >> 6;
    int l15 = lane & 15, kg = lane >> 4;
    int js = t >> 2, sub = t & 3;
    int keyj = swzkey(js);
    const float* xrow0 = x + ((size_t)(b*CC + js)*HH + grp)*WW;
    const ushort* gwrow = gw + ((size_t)(b*CC + js) << 12);
    f32x4 acc[8][3];
    #pragma unroll
    for (int i = 0; i < 8; ++i)
        #pragma unroll
        for (int q = 0; q < 3; ++q) acc[i][q] = (f32x4){0.f,0.f,0.f,0.f};
    float tacc = 0.f, ps0 = 0.f, ps1 = 0.f;
    int H0 = kq*4;
    float4 xa, xbv, xc, xd;
    uint4 gr;
    {
        const float* xp = xrow0 + (2*H0)*WW + sub*16;
        xa = *(const float4*)(xp);
        xbv = *(const float4*)(xp + 4);
        xc = *(const float4*)(xp + 8);
        xd = *(const float4*)(xp + 12);
        gr = *(const uint4*)(gwrow + H0*64 + sub*8);
    }
    for (int s = 0; s < 8; ++s) {
        int cur = s & 1;
        ushort* tb = tokb + cur*(3*128*32);
        if (grp == 0) {
            tacc += bf2f((ushort)gr.x) + bf2f((ushort)(gr.x >> 16))
                  + bf2f((ushort)gr.y) + bf2f((ushort)(gr.y >> 16))
                  + bf2f((ushort)gr.z) + bf2f((ushort)(gr.z >> 16))
                  + bf2f((ushort)gr.w) + bf2f((ushort)(gr.w >> 16));
        }
        ps0 += xa.x + xa.z + xbv.x + xbv.z + xc.x + xc.z + xd.x + xd.z;
        ps1 += xa.y + xa.w + xbv.y + xbv.w + xc.y + xc.w + xd.y + xd.w;
        {
            unsigned lo0 = (unsigned)f2bf(xa.x) | ((unsigned)f2bf(xa.z) << 16);
            unsigned lo1 = (unsigned)f2bf(xbv.x) | ((unsigned)f2bf(xbv.z) << 16);
            unsigned lo2 = (unsigned)f2bf(xc.x) | ((unsigned)f2bf(xc.z) << 16);
            unsigned lo3 = (unsigned)f2bf(xd.x) | ((unsigned)f2bf(xd.z) << 16);
            unsigned hi0 = (unsigned)f2bf(xa.y) | ((unsigned)f2bf(xa.w) << 16);
            unsigned hi1 = (unsigned)f2bf(xbv.y) | ((unsigned)f2bf(xbv.w) << 16);
            unsigned hi2 = (unsigned)f2bf(xc.y) | ((unsigned)f2bf(xc.w) << 16);
            unsigned hi3 = (unsigned)f2bf(xd.y) | ((unsigned)f2bf(xd.w) << 16);
            uint4 lov = {lo0, lo1, lo2, lo3};
            uint4 hiv = {hi0, hi1, hi2, hi3};
            int chs = (sub ^ keyj) << 3;
            *(uint4*)(tb + (1*128 + js)*32 + chs) = lov;
            *(uint4*)(tb + (2*128 + js)*32 + chs) = hiv;
            *(uint4*)(tb + (0*128 + js)*32 + chs) = gr;
        }
        if (s < 7) {
            int sn = s + 1;
            int h = H0 + (sn >> 1), whalf = sn & 1;
            const float* xp = xrow0 + (2*h)*WW + whalf*64 + sub*16;
            xa = *(const float4*)(xp);
            xbv = *(const float4*)(xp + 4);
            xc = *(const float4*)(xp + 8);
            xd = *(const float4*)(xp + 12);
            gr = *(const uint4*)(gwrow + h*64 + whalf*32 + sub*8);
        }
        __syncthreads();
        const ushort* tb2 = tokb + cur*(3*128*32);
        short8 af[8];
        #pragma unroll
        for (int f = 0; f < 8; ++f) {
            int row = f*16 + l15;
            af[f] = *(const short8*)(tb2 + row*32 + ((kg ^ swzkey(row)) << 3));
        }
        if (grp == 0) {
            #pragma unroll
            for (int q = 0; q < 3; ++q) {
                int nf = wid*3 + q;
                int pl = nf >> 3, jr = (nf & 7)*16 + l15;
                short8 bf = *(const short8*)(tb2 + (pl*128 + jr)*32 + ((kg ^ swzkey(jr)) << 3));
                #pragma unroll
                for (int f = 0; f < 8; ++f)
                    acc[f][q] = __builtin_amdgcn_mfma_f32_16x16x32_bf16(af[f], bf, acc[f][q], 0, 0, 0);
            }
        } else {
            #pragma unroll
            for (int q = 0; q < 2; ++q) {
                int nf = wid*2 + q;
                int pl = 1 + (nf >> 3), jr = (nf & 7)*16 + l15;
                short8 bf = *(const short8*)(tb2 + (pl*128 + jr)*32 + ((kg ^ swzkey(jr)) << 3));
                #pragma unroll
                for (int f = 0; f < 8; ++f)
                    acc[f][q] = __builtin_amdgcn_mfma_f32_16x16x32_bf16(af[f], bf, acc[f][q], 0, 0, 0);
            }
        }
    }
    ps0 += __shfl_xor(ps0, 1); ps0 += __shfl_xor(ps0, 2);
    ps1 += __shfl_xor(ps1, 1); ps1 += __shfl_xor(ps1, 2);
    if (grp == 0) {
        tacc += __shfl_xor(tacc, 1); tacc += __shfl_xor(tacc, 2);
        if (sub == 0) Tg[(size_t)(b*16 + kq)*128 + js] = tacc;
    }
    if (sub == 0) {
        float* tx = Txg + (((size_t)(b*16 + kq)*2 + grp)*2)*128;
        tx[js] = ps0;
        tx[128 + js] = ps1;
    }
    ushort* gp = Gpart + (size_t)(b*16 + kq)*81920;
    int nq = (grp == 0) ? 3 : 2;
    int nbase = (grp == 0) ? 0 : 384;
    #pragma unroll
    for (int f = 0; f < 8; ++f)
        #pragma unroll
        for (int q = 0; q < 3; ++q) {
            if (q < nq) {
                int n = nbase + (wid*nq + q)*16 + l15;
                uint2 pk;
                pk.x = (unsigned)f2bf(acc[f][q][0]) | ((unsigned)f2bf(acc[f][q][1]) << 16);
                pk.y = (unsigned)f2bf(acc[f][q][2]) | ((unsigned)f2bf(acc[f][q][3]) << 16);
                *(uint2*)(gp + ((size_t)(f*4 + kg)*640 + n)*4) = pk;
            }
        }
}

// ---- combine2: partial S over iq: parallel bf16-Gpart reduce + bilinear ----
__global__ __launch_bounds__(256) void combine2_kernel(
    const ushort* __restrict__ Gpart, const float* __restrict__ qkv_w,
    float* __restrict__ Spart2)
{
    __shared__ float Gm[32*128];   // 16 KB
    int blk = blockIdx.x;
    int iq = blk & 3, bm = blk >> 2;
    int b = bm / 5, m = bm - b*5;
    int t = threadIdx.x;
    for (int e = t; e < 1024; e += 256) {
        int qi = e >> 7, j = e & 127;
        float s0=0.f, s1=0.f, s2=0.f, s3=0.f;
        #pragma unroll
        for (int kq = 0; kq < 16; ++kq) {
            uint2 v = *(const uint2*)(Gpart + (size_t)(b*16 + kq)*81920
                        + ((size_t)(iq*8 + qi)*640 + m*128 + j)*4);
            s0 += bf2f((ushort)v.x); s1 += bf2f((ushort)(v.x >> 16));
            s2 += bf2f((ushort)v.y); s3 += bf2f((ushort)(v.y >> 16));
        }
        Gm[(qi*4 + 0)*128 + j] = s0;
        Gm[(qi*4 + 1)*128 + j] = s1;
        Gm[(qi*4 + 2)*128 + j] = s2;
        Gm[(qi*4 + 3)*128 + j] = s3;
    }
    __syncthreads();
    int c = t >> 1, jh = t & 1;
    float wkr[64];
    const float* wkp = qkv_w + (size_t)(128 + c)*128 + jh*64;
    #pragma unroll
    for (int q = 0; q < 16; ++q)
        *(float4*)&wkr[q*4] = ((const float4*)wkp)[q];
    const float* wqp = qkv_w + (size_t)c*128 + iq*32;
    float acc = 0.f;
    for (int i = 0; i < 32; ++i) {
        const float4* gr4 = (const float4*)(Gm + i*128 + jh*64);
        float val = 0.f;
        #pragma unroll
        for (int q = 0; q < 16; ++q) {
            float4 g4 = gr4[q];
            val += wkr[q*4+0]*g4.x + wkr[q*4+1]*g4.y
                 + wkr[q*4+2]*g4.z + wkr[q*4+3]*g4.w;
        }
        acc += wqp[i]*val;
    }
    acc += __shfl_xor(acc, 1);
    if (jh == 0) Spart2[((size_t)bm*4 + iq)*128 + c] = acc;
}

// ---- softmax + exact bias terms; block 0 also computes cvec ----
__global__ __launch_bounds__(128) void softmax_attn(
    const float* __restrict__ Spart2, const float* __restrict__ Tg,
    const float* __restrict__ Txg, const float* __restrict__ qkv_w,
    const float* __restrict__ qkv_b, const float* __restrict__ proj_w,
    const float* __restrict__ proj_b, float* __restrict__ attn,
    float* __restrict__ cvec)
{
    __shared__ float Ts[5*128];
    int b = blockIdx.x, t = threadIdx.x;
    if (b == 0) {
        float s = proj_b[t];
        const float* pr = proj_w + t*CC;
        const float* bv = qkv_b + 2*CC;
        for (int c = 0; c < CC; ++c) s += pr[c]*bv[c];
        cvec[t] = s;
    }
    #pragma unroll
    for (int v = 0; v < 5; ++v) {
        float s = 0.f;
        if (v == 0) {
            for (int p = 0; p < 16; ++p) s += Tg[(size_t)(b*16 + p)*128 + t];
        } else {
            int grp = (v - 1) >> 1, pi = (v - 1) & 1;
            for (int p = 0; p < 16; ++p)
                s += Txg[(((size_t)(b*16 + p)*2 + grp)*2 + pi)*128 + t];
        }
        Ts[v*128 + t] = s;
    }
    __syncthreads();
    int c = t;
    float bq = qkv_b[c], bk = qkv_b[128 + c];
    const float* wqr = qkv_w + (size_t)c*128;
    const float* wkr = qkv_w + (size_t)(128 + c)*128;
    float t0d = 0.f;
    for (int j = 0; j < 128; ++j) t0d += wqr[j]*Ts[j];
    float s5[5];
    #pragma unroll
    for (int m = 0; m < 5; ++m) {
        float km = 0.f;
        for (int j = 0; j < 128; ++j) km += wkr[j]*Ts[m*128 + j];
        float ss = 0.f;
        #pragma unroll
        for (int iq = 0; iq < 4; ++iq)
            ss += Spart2[((size_t)(b*5 + m)*4 + iq)*128 + c];
        s5[m] = ss + bq*km + bk*t0d + 4096.0f*bq*bk;
    }
    const float scale = 0.08838834764831845f;  // 1/sqrt(128)
    float mx = s5[0]*scale;
    #pragma unroll
    for (int m = 1; m < 5; ++m) mx = fmaxf(mx, s5[m]*scale);
    float e[5], tot = 0.f;
    #pragma unroll
    for (int m = 0; m < 5; ++m) { e[m] = expf(s5[m]*scale - mx); tot += e[m]; }
    float inv = 1.f/tot;
    #pragma unroll
    for (int m = 0; m < 5; ++m) attn[(size_t)(b*128 + c)*5 + m] = e[m]*inv;
}

// ---- pw: PW_m[b][:, jq*32..+31] = (proj .* attn_m) @ Wv-slab; grid 320 ----
__global__ __launch_bounds__(256) void pw_kernel(
    const float* __restrict__ qkv_w, const float* __restrict__ proj_w,
    const float* __restrict__ attn, ushort* __restrict__ PW)
{
    __shared__ float attns[CC];
    __shared__ float wvs[128*33];   // padded
    int blk = blockIdx.x;
    int jq = blk & 3, bm = blk >> 2;
    int b = bm / 5, m = bm - b*5;
    int t = threadIdx.x;
    if (t < 128) attns[t] = attn[(size_t)(b*CC + t)*5 + m];
    for (int idx = t; idx < 128*32; idx += 256) {
        int row = idx >> 5, col = idx & 31;
        wvs[row*33 + col] = qkv_w[(size_t)(2*CC + row)*CC + jq*32 + col];
    }
    __syncthreads();
    int d = t >> 1, jh = t & 1;
    float acc[16];
    #pragma unroll
    for (int j = 0; j < 16; ++j) acc[j] = 0.f;
    const float* pr = proj_w + (size_t)d*CC;
    for (int c = 0; c < 128; ++c) {
        float a = pr[c]*attns[c];
        const float* wr = wvs + c*33 + jh*16;
        #pragma unroll
        for (int j = 0; j < 16; ++j) acc[j] += a*wr[j];
    }
    ushort* dst = PW + ((size_t)(b*5 + m) << 14) + (size_t)d*CC + jq*32 + jh*16;
    #pragma unroll
    for (int j = 0; j < 16; ++j) dst[j] = f2bf(acc[j]);
}

// ---- phase B: Y[l][c_out] = sum_{m,c} tok[m][l][c]*PW_m[c_out][c] + cvec ----
// 64-l blocks (one h-row), 512 threads, single-barrier staging, 80 KB LDS.
__global__ __launch_bounds__(512) void y_kernel(
    const float* __restrict__ x, const ushort* __restrict__ gw,
    const ushort* __restrict__ PW, const float* __restrict__ cvec,
    float* __restrict__ out)
{
    __shared__ __align__(16) ushort tok[5*64*128];   // 80 KB; ylds overlays
    int t = threadIdx.x;
    int blk = blockIdx.x;
    int b = blk >> 6, h = blk & 63;
    int lane = t & 63, wave = t >> 6;
    int l15 = lane & 15, kg = lane >> 4;
    int swz = (l15 & 7) << 3;
    int lbase = (wave >> 2)*32;
    int cq = (wave & 3)*32;
    int c = t >> 2, r2 = t & 3;
    int r = r2 >> 1, half = r2 & 1;
    const ushort* gsrc = gw + ((size_t)(b*CC + c) << 12) + h*64 + r2*16;
    uint4 g0 = *(const uint4*)gsrc;
    uint4 g1 = *(const uint4*)(gsrc + 8);
    const float* xrow = x + ((size_t)(b*CC + c)*HH + 2*h + r)*WW + half*64;
    float4 xv[16];
    #pragma unroll
    for (int i = 0; i < 16; ++i) xv[i] = ((const float4*)xrow)[i];
    {
        unsigned wd[8] = {g0.x,g0.y,g0.z,g0.w,g1.x,g1.y,g1.z,g1.w};
        #pragma unroll
        for (int k2 = 0; k2 < 8; ++k2) {
            int lp0 = r2*16 + 2*k2, lp1 = lp0 + 1;
            tok[lp0*128 + (c ^ ((lp0 & 7) << 3))] = (ushort)wd[k2];
            tok[lp1*128 + (c ^ ((lp1 & 7) << 3))] = (ushort)(wd[k2] >> 16);
        }
    }
    {
        int mA = (1 + 2*r)*8192, mB = (2 + 2*r)*8192;
        int lb = half*32;
        #pragma unroll
        for (int i = 0; i < 16; ++i) {
            int lp0 = lb + 2*i, lp1 = lp0 + 1;
            int o0 = lp0*128 + (c ^ ((lp0 & 7) << 3));
            int o1 = lp1*128 + (c ^ ((lp1 & 7) << 3));
            tok[mA + o0] = f2bf(xv[i].x);
            tok[mB + o0] = f2bf(xv[i].y);
            tok[mA + o1] = f2bf(xv[i].z);
            tok[mB + o1] = f2bf(xv[i].w);
        }
    }
    __syncthreads();
    f32x4 acc[2][2] = {};
    #pragma unroll
    for (int m = 0; m < 5; ++m) {
        const ushort* pwb = PW + ((size_t)(b*5 + m) << 14)
                          + ((cq + l15) << 7) + (kg << 3);
        #pragma unroll
        for (int kt = 0; kt < 4; ++kt) {
            int ko = (kt*32 + kg*8) ^ swz;
            short8 a0 = *(const short8*)(tok + m*8192 + (lbase + l15     )*128 + ko);
            short8 a1 = *(const short8*)(tok + m*8192 + (lbase + 16 + l15)*128 + ko);
            short8 b0 = *(const short8*)(pwb + kt*32);
            short8 b1 = *(const short8*)(pwb + (16 << 7) + kt*32);
            acc[0][0] = __builtin_amdgcn_mfma_f32_16x16x32_bf16(a0, b0, acc[0][0], 0, 0, 0);
            acc[0][1] = __builtin_amdgcn_mfma_f32_16x16x32_bf16(a0, b1, acc[0][1], 0, 0, 0);
            acc[1][0] = __builtin_amdgcn_mfma_f32_16x16x32_bf16(a1, b0, acc[1][0], 0, 0, 0);
            acc[1][1] = __builtin_amdgcn_mfma_f32_16x16x32_bf16(a1, b1, acc[1][1], 0, 0, 0);
        }
    }
    __syncthreads();
    float* ylds = (float*)tok;   // [128][68]
    #pragma unroll
    for (int mt = 0; mt < 2; ++mt)
        #pragma unroll
        for (int ntl = 0; ntl < 2; ++ntl) {
            int cc = cq + ntl*16 + l15;
            float cv = cvec[cc];
            #pragma unroll
            for (int rr = 0; rr < 4; ++rr) {
                int l = lbase + mt*16 + kg*4 + rr;
                ylds[cc*68 + l] = acc[mt][ntl][rr] + cv;
            }
        }
    __syncthreads();
    int c2 = t >> 2, q = t & 3;
    float* ob = out + ((size_t)(b*CC + c2) << 12) + h*64 + q*16;
    const float* yr = ylds + c2*68 + q*16;
    #pragma unroll
    for (int j = 0; j < 4; ++j)
        ((float4*)ob)[j] = ((const float4*)yr)[j];
}

extern "C" void kernel_launch(void* const* d_in, const int* in_sizes, int n_in,
                              void* d_out, int out_size, void* d_ws, size_t ws_size,
                              hipStream_t stream) {
    const float* x        = (const float*)d_in[0];
    const float* bn_gamma = (const float*)d_in[1];
    const float* bn_beta  = (const float*)d_in[2];
    const float* bn_mean  = (const float*)d_in[3];
    const float* bn_var   = (const float*)d_in[4];
    const float* dw_w     = (const float*)d_in[5];
    const float* dw_b     = (const float*)d_in[6];
    const float* qkv_w    = (const float*)d_in[7];
    const float* qkv_b    = (const float*)d_in[8];
    const float* proj_w   = (const float*)d_in[9];
    const float* proj_b   = (const float*)d_in[10];
    float* out = (float*)d_out;

    char* w = (char*)d_ws;
    ushort* gw     = (ushort*)w; w += (size_t)BB*CC*LL*2;          // 16.8 MB
    ushort* PW     = (ushort*)w; w += (size_t)BB*5*CC*CC*2;        // 2.6 MB
    ushort* Gpart  = (ushort*)w; w += (size_t)BB*16*81920*2;       // 41.9 MB (bf16)
    float*  Tg     = (float*)w;  w += (size_t)BB*16*128*4;         // 131 KB
    float*  Txg    = (float*)w;  w += (size_t)BB*16*2*2*128*4;     // 524 KB
    float*  Spart2 = (float*)w;  w += (size_t)BB*5*4*128*4;        // 164 KB
    float*  attn   = (float*)w;  w += (size_t)BB*CC*5*4;           // 40 KB
    float*  cvec   = (float*)w;  w += (size_t)CC*4;

    guide_kernel<<<dim3(BB*CC, 4), 256, 0, stream>>>(
        x, bn_gamma, bn_beta, bn_mean, bn_var, dw_w, dw_b, gw);
    gram_kernel<<<512, 512, 0, stream>>>(x, gw, Gpart, Tg, Txg);
    combine2_kernel<<<BB*5*4, 256, 0, stream>>>(Gpart, qkv_w, Spart2);
    softmax_attn<<<BB, 128, 0, stream>>>(Spart2, Tg, Txg, qkv_w, qkv_b,
                                         proj_w, proj_b, attn, cvec);
    pw_kernel<<<BB*5*4, 256, 0, stream>>>(qkv_w, proj_w, attn, PW);
    y_kernel<<<BB*64, 512, 0, stream>>>(x, gw, PW, cvec, out);
}

// Round 18
// 193.333 us; speedup vs baseline: 1.2735x; 1.0087x over previous
//
#include <hip/hip_runtime.h>
#include <math.h>

#define BB 16
#define CC 128
#define HH 128
#define WW 128
#define LL 4096

typedef short short8 __attribute__((ext_vector_type(8)));
typedef float f32x4 __attribute__((ext_vector_type(4)));

__device__ __forceinline__ ushort f2bf(float f) {
    union { float f; unsigned u; } un; un.f = f;
    unsigned u = un.u;
    u += 0x7fffu + ((u >> 16) & 1u);   // RNE
    return (ushort)(u >> 16);
}
__device__ __forceinline__ float bf2f(ushort h) {
    union { unsigned u; float f; } un; un.u = ((unsigned)h) << 16;
    return un.f;
}
__device__ __forceinline__ float fast_gelu(float xv) {
    float x2 = xv*xv;
    float arg = xv*(-2.3022100f - 0.1029436f*x2);
    float e = exp2f(arg);
    return xv*__builtin_amdgcn_rcpf(1.f + e);
}
__device__ __forceinline__ int swzkey(int r) { return (r & 3) ^ ((r >> 2) & 3); }

// ---- guide = dwconv7x7_s2(gelu(bn(x))), bf16 out [b][c][64*64] (ty=4, R17) ----
__global__ __launch_bounds__(256) void guide_kernel(
    const float* __restrict__ x, const float* __restrict__ gamma,
    const float* __restrict__ beta, const float* __restrict__ mean,
    const float* __restrict__ var, const float* __restrict__ dww,
    const float* __restrict__ dwb, ushort* __restrict__ gw)
{
    int bc = blockIdx.x;
    int b = bc >> 7, c = bc & 127;
    int ty = blockIdx.y;                       // 0..3
    __shared__ __align__(16) float g[37*144];  // 21.3 KB
    int t = threadIdx.x;
    float wreg[49];
    #pragma unroll
    for (int k = 0; k < 49; ++k) wreg[k] = dww[c*49 + k];
    float bias = dwb[c];
    float scl = gamma[c] * rsqrtf(var[c] + 1e-5f);
    float sft = beta[c] - mean[c]*scl;
    const float* xb = x + (size_t)(b*CC + c)*HH*WW;
    int ihbase = 32*ty - 3;
    #pragma unroll
    for (int k = 0; k < 5; ++k) {
        int idx = k*256 + t;
        if (idx < 37*32) {
            int row = idx >> 5, ch = idx & 31;
            int ih = ihbase + row;
            float4 v4 = {0.f, 0.f, 0.f, 0.f};
            if ((unsigned)ih < 128u) {
                float4 xv = *(const float4*)(xb + ih*WW + 4*ch);
                v4.x = fast_gelu(xv.x*scl + sft);
                v4.y = fast_gelu(xv.y*scl + sft);
                v4.z = fast_gelu(xv.z*scl + sft);
                v4.w = fast_gelu(xv.w*scl + sft);
            }
            int f = (row >> 2) & 3;
            *(float4*)(g + row*144 + 4*((ch + 1) ^ f)) = v4;
        }
    }
    if (t < 74) {
        int row = t >> 1;
        int lc = (t & 1) ? 33 : 0;
        int f = (row >> 2) & 3;
        float4 z4 = {0.f, 0.f, 0.f, 0.f};
        *(float4*)(g + row*144 + 4*(lc ^ f)) = z4;
    }
    __syncthreads();
    int vg = t >> 4, owg = t & 15;
    float a0 = bias, a1 = bias, a2 = bias, a3 = bias;
    #pragma unroll
    for (int kh = 0; kh < 7; ++kh) {
        int rr = 2*vg + kh;
        int f = (rr >> 2) & 3;
        const float* grow = g + rr*144;
        float win[16];
        #pragma unroll
        for (int i = 0; i < 4; ++i) {
            float4 w4 = *(const float4*)(grow + 4*(((2*owg + i) ^ f)));
            win[4*i+0] = w4.x; win[4*i+1] = w4.y;
            win[4*i+2] = w4.z; win[4*i+3] = w4.w;
        }
        #pragma unroll
        for (int kw = 0; kw < 7; ++kw) {
            float wv = wreg[kh*7 + kw];
            a0 += wv * win[kw + 1];
            a1 += wv * win[kw + 3];
            a2 += wv * win[kw + 5];
            a3 += wv * win[kw + 7];
        }
    }
    uint2 pk;
    pk.x = (unsigned)f2bf(a0) | ((unsigned)f2bf(a1) << 16);
    pk.y = (unsigned)f2bf(a2) | ((unsigned)f2bf(a3) << 16);
    *(uint2*)(gw + ((size_t)(b*CC + c) << 12) + (ty*16 + vg)*64 + 4*owg) = pk;
}

// ---- Gram_m[i,j] = sum_l t0[i,l]*t_m[j,l]; kq=16; bf16-packed output + T partials ----
__global__ __launch_bounds__(512) void gram_kernel(
    const float* __restrict__ x, const ushort* __restrict__ gw,
    ushort* __restrict__ Gpart, float* __restrict__ Tg, float* __restrict__ Txg)
{
    __shared__ __align__(16) ushort tokb[2*3*128*32];
    int t = threadIdx.x;
    int blk = blockIdx.x;
    int b = blk >> 5, kq = (blk >> 1) & 15, grp = blk & 1;
    int lane = t & 63, wid = t >> 6;
    int l15 = lane & 15, kg = lane >> 4;
    int js = t >> 2, sub = t & 3;
    int keyj = swzkey(js);
    const float* xrow0 = x + ((size_t)(b*CC + js)*HH + grp)*WW;
    const ushort* gwrow = gw + ((size_t)(b*CC + js) << 12);
    f32x4 acc[8][3];
    #pragma unroll
    for (int i = 0; i < 8; ++i)
        #pragma unroll
        for (int q = 0; q < 3; ++q) acc[i][q] = (f32x4){0.f,0.f,0.f,0.f};
    float tacc = 0.f, ps0 = 0.f, ps1 = 0.f;
    int H0 = kq*4;
    float4 xa, xbv, xc, xd;
    uint4 gr;
    {
        const float* xp = xrow0 + (2*H0)*WW + sub*16;
        xa = *(const float4*)(xp);
        xbv = *(const float4*)(xp + 4);
        xc = *(const float4*)(xp + 8);
        xd = *(const float4*)(xp + 12);
        gr = *(const uint4*)(gwrow + H0*64 + sub*8);
    }
    for (int s = 0; s < 8; ++s) {
        int cur = s & 1;
        ushort* tb = tokb + cur*(3*128*32);
        if (grp == 0) {
            tacc += bf2f((ushort)gr.x) + bf2f((ushort)(gr.x >> 16))
                  + bf2f((ushort)gr.y) + bf2f((ushort)(gr.y >> 16))
                  + bf2f((ushort)gr.z) + bf2f((ushort)(gr.z >> 16))
                  + bf2f((ushort)gr.w) + bf2f((ushort)(gr.w >> 16));
        }
        ps0 += xa.x + xa.z + xbv.x + xbv.z + xc.x + xc.z + xd.x + xd.z;
        ps1 += xa.y + xa.w + xbv.y + xbv.w + xc.y + xc.w + xd.y + xd.w;
        {
            unsigned lo0 = (unsigned)f2bf(xa.x) | ((unsigned)f2bf(xa.z) << 16);
            unsigned lo1 = (unsigned)f2bf(xbv.x) | ((unsigned)f2bf(xbv.z) << 16);
            unsigned lo2 = (unsigned)f2bf(xc.x) | ((unsigned)f2bf(xc.z) << 16);
            unsigned lo3 = (unsigned)f2bf(xd.x) | ((unsigned)f2bf(xd.z) << 16);
            unsigned hi0 = (unsigned)f2bf(xa.y) | ((unsigned)f2bf(xa.w) << 16);
            unsigned hi1 = (unsigned)f2bf(xbv.y) | ((unsigned)f2bf(xbv.w) << 16);
            unsigned hi2 = (unsigned)f2bf(xc.y) | ((unsigned)f2bf(xc.w) << 16);
            unsigned hi3 = (unsigned)f2bf(xd.y) | ((unsigned)f2bf(xd.w) << 16);
            uint4 lov = {lo0, lo1, lo2, lo3};
            uint4 hiv = {hi0, hi1, hi2, hi3};
            int chs = (sub ^ keyj) << 3;
            *(uint4*)(tb + (1*128 + js)*32 + chs) = lov;
            *(uint4*)(tb + (2*128 + js)*32 + chs) = hiv;
            *(uint4*)(tb + (0*128 + js)*32 + chs) = gr;
        }
        if (s < 7) {
            int sn = s + 1;
            int h = H0 + (sn >> 1), whalf = sn & 1;
            const float* xp = xrow0 + (2*h)*WW + whalf*64 + sub*16;
            xa = *(const float4*)(xp);
            xbv = *(const float4*)(xp + 4);
            xc = *(const float4*)(xp + 8);
            xd = *(const float4*)(xp + 12);
            gr = *(const uint4*)(gwrow + h*64 + whalf*32 + sub*8);
        }
        __syncthreads();
        const ushort* tb2 = tokb + cur*(3*128*32);
        short8 af[8];
        #pragma unroll
        for (int f = 0; f < 8; ++f) {
            int row = f*16 + l15;
            af[f] = *(const short8*)(tb2 + row*32 + ((kg ^ swzkey(row)) << 3));
        }
        if (grp == 0) {
            #pragma unroll
            for (int q = 0; q < 3; ++q) {
                int nf = wid*3 + q;
                int pl = nf >> 3, jr = (nf & 7)*16 + l15;
                short8 bf = *(const short8*)(tb2 + (pl*128 + jr)*32 + ((kg ^ swzkey(jr)) << 3));
                #pragma unroll
                for (int f = 0; f < 8; ++f)
                    acc[f][q] = __builtin_amdgcn_mfma_f32_16x16x32_bf16(af[f], bf, acc[f][q], 0, 0, 0);
            }
        } else {
            #pragma unroll
            for (int q = 0; q < 2; ++q) {
                int nf = wid*2 + q;
                int pl = 1 + (nf >> 3), jr = (nf & 7)*16 + l15;
                short8 bf = *(const short8*)(tb2 + (pl*128 + jr)*32 + ((kg ^ swzkey(jr)) << 3));
                #pragma unroll
                for (int f = 0; f < 8; ++f)
                    acc[f][q] = __builtin_amdgcn_mfma_f32_16x16x32_bf16(af[f], bf, acc[f][q], 0, 0, 0);
            }
        }
    }
    ps0 += __shfl_xor(ps0, 1); ps0 += __shfl_xor(ps0, 2);
    ps1 += __shfl_xor(ps1, 1); ps1 += __shfl_xor(ps1, 2);
    if (grp == 0) {
        tacc += __shfl_xor(tacc, 1); tacc += __shfl_xor(tacc, 2);
        if (sub == 0) Tg[(size_t)(b*16 + kq)*128 + js] = tacc;
    }
    if (sub == 0) {
        float* tx = Txg + (((size_t)(b*16 + kq)*2 + grp)*2)*128;
        tx[js] = ps0;
        tx[128 + js] = ps1;
    }
    ushort* gp = Gpart + (size_t)(b*16 + kq)*81920;
    int nq = (grp == 0) ? 3 : 2;
    int nbase = (grp == 0) ? 0 : 384;
    #pragma unroll
    for (int f = 0; f < 8; ++f)
        #pragma unroll
        for (int q = 0; q < 3; ++q) {
            if (q < nq) {
                int n = nbase + (wid*nq + q)*16 + l15;
                uint2 pk;
                pk.x = (unsigned)f2bf(acc[f][q][0]) | ((unsigned)f2bf(acc[f][q][1]) << 16);
                pk.y = (unsigned)f2bf(acc[f][q][2]) | ((unsigned)f2bf(acc[f][q][3]) << 16);
                *(uint2*)(gp + ((size_t)(f*4 + kg)*640 + n)*4) = pk;
            }
        }
}

// ---- combine2: partial S over iq: parallel bf16-Gpart reduce + bilinear ----
__global__ __launch_bounds__(256) void combine2_kernel(
    const ushort* __restrict__ Gpart, const float* __restrict__ qkv_w,
    float* __restrict__ Spart2)
{
    __shared__ float Gm[32*128];   // 16 KB
    int blk = blockIdx.x;
    int iq = blk & 3, bm = blk >> 2;
    int b = bm / 5, m = bm - b*5;
    int t = threadIdx.x;
    for (int e = t; e < 1024; e += 256) {
        int qi = e >> 7, j = e & 127;
        float s0=0.f, s1=0.f, s2=0.f, s3=0.f;
        #pragma unroll
        for (int kq = 0; kq < 16; ++kq) {
            uint2 v = *(const uint2*)(Gpart + (size_t)(b*16 + kq)*81920
                        + ((size_t)(iq*8 + qi)*640 + m*128 + j)*4);
            s0 += bf2f((ushort)v.x); s1 += bf2f((ushort)(v.x >> 16));
            s2 += bf2f((ushort)v.y); s3 += bf2f((ushort)(v.y >> 16));
        }
        Gm[(qi*4 + 0)*128 + j] = s0;
        Gm[(qi*4 + 1)*128 + j] = s1;
        Gm[(qi*4 + 2)*128 + j] = s2;
        Gm[(qi*4 + 3)*128 + j] = s3;
    }
    __syncthreads();
    int c = t >> 1, jh = t & 1;
    float wkr[64];
    const float* wkp = qkv_w + (size_t)(128 + c)*128 + jh*64;
    #pragma unroll
    for (int q = 0; q < 16; ++q)
        *(float4*)&wkr[q*4] = ((const float4*)wkp)[q];
    const float* wqp = qkv_w + (size_t)c*128 + iq*32;
    float acc = 0.f;
    for (int i = 0; i < 32; ++i) {
        const float4* gr4 = (const float4*)(Gm + i*128 + jh*64);
        float val = 0.f;
        #pragma unroll
        for (int q = 0; q < 16; ++q) {
            float4 g4 = gr4[q];
            val += wkr[q*4+0]*g4.x + wkr[q*4+1]*g4.y
                 + wkr[q*4+2]*g4.z + wkr[q*4+3]*g4.w;
        }
        acc += wqp[i]*val;
    }
    acc += __shfl_xor(acc, 1);
    if (jh == 0) Spart2[((size_t)bm*4 + iq)*128 + c] = acc;
}

// ---- softmax + exact bias terms; block 0 also computes cvec ----
__global__ __launch_bounds__(128) void softmax_attn(
    const float* __restrict__ Spart2, const float* __restrict__ Tg,
    const float* __restrict__ Txg, const float* __restrict__ qkv_w,
    const float* __restrict__ qkv_b, const float* __restrict__ proj_w,
    const float* __restrict__ proj_b, float* __restrict__ attn,
    float* __restrict__ cvec)
{
    __shared__ float Ts[5*128];
    int b = blockIdx.x, t = threadIdx.x;
    if (b == 0) {
        float s = proj_b[t];
        const float* pr = proj_w + t*CC;
        const float* bv = qkv_b + 2*CC;
        for (int c = 0; c < CC; ++c) s += pr[c]*bv[c];
        cvec[t] = s;
    }
    #pragma unroll
    for (int v = 0; v < 5; ++v) {
        float s = 0.f;
        if (v == 0) {
            for (int p = 0; p < 16; ++p) s += Tg[(size_t)(b*16 + p)*128 + t];
        } else {
            int grp = (v - 1) >> 1, pi = (v - 1) & 1;
            for (int p = 0; p < 16; ++p)
                s += Txg[(((size_t)(b*16 + p)*2 + grp)*2 + pi)*128 + t];
        }
        Ts[v*128 + t] = s;
    }
    __syncthreads();
    int c = t;
    float bq = qkv_b[c], bk = qkv_b[128 + c];
    const float* wqr = qkv_w + (size_t)c*128;
    const float* wkr = qkv_w + (size_t)(128 + c)*128;
    float t0d = 0.f;
    for (int j = 0; j < 128; ++j) t0d += wqr[j]*Ts[j];
    float s5[5];
    #pragma unroll
    for (int m = 0; m < 5; ++m) {
        float km = 0.f;
        for (int j = 0; j < 128; ++j) km += wkr[j]*Ts[m*128 + j];
        float ss = 0.f;
        #pragma unroll
        for (int iq = 0; iq < 4; ++iq)
            ss += Spart2[((size_t)(b*5 + m)*4 + iq)*128 + c];
        s5[m] = ss + bq*km + bk*t0d + 4096.0f*bq*bk;
    }
    const float scale = 0.08838834764831845f;  // 1/sqrt(128)
    float mx = s5[0]*scale;
    #pragma unroll
    for (int m = 1; m < 5; ++m) mx = fmaxf(mx, s5[m]*scale);
    float e[5], tot = 0.f;
    #pragma unroll
    for (int m = 0; m < 5; ++m) { e[m] = expf(s5[m]*scale - mx); tot += e[m]; }
    float inv = 1.f/tot;
    #pragma unroll
    for (int m = 0; m < 5; ++m) attn[(size_t)(b*128 + c)*5 + m] = e[m]*inv;
}

// ---- pw: PW_m[b][:, jq*32..+31] = (proj .* attn_m) @ Wv-slab; grid 320 ----
__global__ __launch_bounds__(256) void pw_kernel(
    const float* __restrict__ qkv_w, const float* __restrict__ proj_w,
    const float* __restrict__ attn, ushort* __restrict__ PW)
{
    __shared__ float attns[CC];
    __shared__ float wvs[128*33];   // padded
    int blk = blockIdx.x;
    int jq = blk & 3, bm = blk >> 2;
    int b = bm / 5, m = bm - b*5;
    int t = threadIdx.x;
    if (t < 128) attns[t] = attn[(size_t)(b*CC + t)*5 + m];
    for (int idx = t; idx < 128*32; idx += 256) {
        int row = idx >> 5, col = idx & 31;
        wvs[row*33 + col] = qkv_w[(size_t)(2*CC + row)*CC + jq*32 + col];
    }
    __syncthreads();
    int d = t >> 1, jh = t & 1;
    float acc[16];
    #pragma unroll
    for (int j = 0; j < 16; ++j) acc[j] = 0.f;
    const float* pr = proj_w + (size_t)d*CC;
    for (int c = 0; c < 128; ++c) {
        float a = pr[c]*attns[c];
        const float* wr = wvs + c*33 + jh*16;
        #pragma unroll
        for (int j = 0; j < 16; ++j) acc[j] += a*wr[j];
    }
    ushort* dst = PW + ((size_t)(b*5 + m) << 14) + (size_t)d*CC + jq*32 + jh*16;
    #pragma unroll
    for (int j = 0; j < 16; ++j) dst[j] = f2bf(acc[j]);
}

// ---- phase B: Y[l][c_out] = sum_{m,c} tok[m][l][c]*PW_m[c_out][c] + cvec ----
// R12/R14 proven form: 32-l blocks, 256 threads, single barrier, 40 KB LDS.
__global__ __launch_bounds__(256) void y_kernel(
    const float* __restrict__ x, const ushort* __restrict__ gw,
    const ushort* __restrict__ PW, const float* __restrict__ cvec,
    float* __restrict__ out)
{
    __shared__ __align__(16) ushort tok[5*32*128];   // 40 KB; ylds overlays
    int t = threadIdx.x;
    int blk = blockIdx.x;
    int b = blk >> 7, chunk = blk & 127;
    int h = chunk >> 1, whalf = chunk & 1;
    int lane = t & 63, wave = t >> 6;
    int l15 = lane & 15, kg = lane >> 4;
    int swz = (l15 & 7) << 3;
    int c = t >> 1, r = t & 1;
    const ushort* gsrc = gw + ((size_t)(b*CC + c) << 12) + h*64 + whalf*32 + r*16;
    uint4 g0 = *(const uint4*)gsrc;
    uint4 g1 = *(const uint4*)(gsrc + 8);
    const float* xrow = x + ((size_t)(b*CC + c)*HH + 2*h + r)*WW + whalf*64;
    float4 xv[16];
    #pragma unroll
    for (int i = 0; i < 16; ++i) xv[i] = ((const float4*)xrow)[i];
    {
        unsigned wd[8] = {g0.x,g0.y,g0.z,g0.w,g1.x,g1.y,g1.z,g1.w};
        #pragma unroll
        for (int k2 = 0; k2 < 8; ++k2) {
            int lp0 = r*16 + 2*k2, lp1 = lp0 + 1;
            tok[lp0*128 + (c ^ ((lp0 & 7) << 3))] = (ushort)wd[k2];
            tok[lp1*128 + (c ^ ((lp1 & 7) << 3))] = (ushort)(wd[k2] >> 16);
        }
    }
    {
        int mA = (1 + 2*r)*4096, mB = (2 + 2*r)*4096;
        #pragma unroll
        for (int i = 0; i < 16; ++i) {
            int lp0 = 2*i, lp1 = 2*i + 1;
            int o0 = lp0*128 + (c ^ ((lp0 & 7) << 3));
            int o1 = lp1*128 + (c ^ ((lp1 & 7) << 3));
            tok[mA + o0] = f2bf(xv[i].x);
            tok[mB + o0] = f2bf(xv[i].y);
            tok[mA + o1] = f2bf(xv[i].z);
            tok[mB + o1] = f2bf(xv[i].w);
        }
    }
    __syncthreads();
    f32x4 acc[2][2] = {};
    #pragma unroll
    for (int m = 0; m < 5; ++m) {
        const ushort* pwb = PW + ((size_t)(b*5 + m) << 14)
                          + ((wave*32 + l15) << 7) + (kg << 3);
        #pragma unroll
        for (int kt = 0; kt < 4; ++kt) {
            int ko = (kt*32 + kg*8) ^ swz;
            short8 a0 = *(const short8*)(tok + m*4096 + (l15     )*128 + ko);
            short8 a1 = *(const short8*)(tok + m*4096 + (16 + l15)*128 + ko);
            short8 b0 = *(const short8*)(pwb + kt*32);
            short8 b1 = *(const short8*)(pwb + (16 << 7) + kt*32);
            acc[0][0] = __builtin_amdgcn_mfma_f32_16x16x32_bf16(a0, b0, acc[0][0], 0, 0, 0);
            acc[0][1] = __builtin_amdgcn_mfma_f32_16x16x32_bf16(a0, b1, acc[0][1], 0, 0, 0);
            acc[1][0] = __builtin_amdgcn_mfma_f32_16x16x32_bf16(a1, b0, acc[1][0], 0, 0, 0);
            acc[1][1] = __builtin_amdgcn_mfma_f32_16x16x32_bf16(a1, b1, acc[1][1], 0, 0, 0);
        }
    }
    __syncthreads();
    float* ylds = (float*)tok;   // [128][36]
    #pragma unroll
    for (int mt = 0; mt < 2; ++mt)
        #pragma unroll
        for (int ntl = 0; ntl < 2; ++ntl) {
            int cc = wave*32 + ntl*16 + l15;
            float cv = cvec[cc];
            #pragma unroll
            for (int rr = 0; rr < 4; ++rr) {
                int l = mt*16 + kg*4 + rr;
                ylds[cc*36 + l] = acc[mt][ntl][rr] + cv;
            }
        }
    __syncthreads();
    int c2 = t >> 1, half = t & 1;
    float* ob = out + ((size_t)(b*CC + c2) << 12) + h*64 + whalf*32 + half*16;
    const float* yr = ylds + c2*36 + half*16;
    #pragma unroll
    for (int j = 0; j < 4; ++j)
        ((float4*)ob)[j] = ((const float4*)yr)[j];
}

extern "C" void kernel_launch(void* const* d_in, const int* in_sizes, int n_in,
                              void* d_out, int out_size, void* d_ws, size_t ws_size,
                              hipStream_t stream) {
    const float* x        = (const float*)d_in[0];
    const float* bn_gamma = (const float*)d_in[1];
    const float* bn_beta  = (const float*)d_in[2];
    const float* bn_mean  = (const float*)d_in[3];
    const float* bn_var   = (const float*)d_in[4];
    const float* dw_w     = (const float*)d_in[5];
    const float* dw_b     = (const float*)d_in[6];
    const float* qkv_w    = (const float*)d_in[7];
    const float* qkv_b    = (const float*)d_in[8];
    const float* proj_w   = (const float*)d_in[9];
    const float* proj_b   = (const float*)d_in[10];
    float* out = (float*)d_out;

    char* w = (char*)d_ws;
    ushort* gw     = (ushort*)w; w += (size_t)BB*CC*LL*2;          // 16.8 MB
    ushort* PW     = (ushort*)w; w += (size_t)BB*5*CC*CC*2;        // 2.6 MB
    ushort* Gpart  = (ushort*)w; w += (size_t)BB*16*81920*2;       // 41.9 MB (bf16)
    float*  Tg     = (float*)w;  w += (size_t)BB*16*128*4;         // 131 KB
    float*  Txg    = (float*)w;  w += (size_t)BB*16*2*2*128*4;     // 524 KB
    float*  Spart2 = (float*)w;  w += (size_t)BB*5*4*128*4;        // 164 KB
    float*  attn   = (float*)w;  w += (size_t)BB*CC*5*4;           // 40 KB
    float*  cvec   = (float*)w;  w += (size_t)CC*4;

    guide_kernel<<<dim3(BB*CC, 4), 256, 0, stream>>>(
        x, bn_gamma, bn_beta, bn_mean, bn_var, dw_w, dw_b, gw);
    gram_kernel<<<512, 512, 0, stream>>>(x, gw, Gpart, Tg, Txg);
    combine2_kernel<<<BB*5*4, 256, 0, stream>>>(Gpart, qkv_w, Spart2);
    softmax_attn<<<BB, 128, 0, stream>>>(Spart2, Tg, Txg, qkv_w, qkv_b,
                                         proj_w, proj_b, attn, cvec);
    pw_kernel<<<BB*5*4, 256, 0, stream>>>(qkv_w, proj_w, attn, PW);
    y_kernel<<<2048, 256, 0, stream>>>(x, gw, PW, cvec, out);
}